// Round 5
// baseline (235.338 us; speedup 1.0000x reference)
//
#include <hip/hip_runtime.h>
#include <math.h>

// Problem constants (fixed by setup_inputs):
//   B=4, N=2048, D=512, H=4, A=64, V=64, L=6400
//   qkvb (bf16, L x 768): [0:256)=v, [256:512)=q, [512:768)=k
//   A2   (bf16, L x 1024): [0:256)=u, [256:768)=x, [768:1024)=y
#define NSEQ 2048
#define PIT 72   // LDS row pitch (bf16 elems): 144B rows -> 16B aligned, 2-way banks only

#if defined(__has_builtin)
#if __has_builtin(__builtin_amdgcn_mfma_f32_16x16x16bf16_1k)
#define HAS_MFMA16 1
#endif
#endif
#ifndef HAS_MFMA16
#define HAS_MFMA16 0
#endif

typedef __attribute__((ext_vector_type(8))) short short8;   // 8 bf16 = 4 VGPR
typedef __attribute__((ext_vector_type(4))) short short4v;  // 4 bf16 = 2 VGPR
typedef __attribute__((ext_vector_type(4))) float f32x4;    // MFMA acc

__device__ __forceinline__ float silu_f(float z) {
    return z / (1.f + __expf(-z));
}

__device__ __forceinline__ unsigned short f2bf(float f) {
    unsigned int u = __float_as_uint(f);
    u += 0x7fffu + ((u >> 16) & 1u);   // RNE (finite inputs only)
    return (unsigned short)(u >> 16);
}

// ---------------- transpose + cast: Wt[c][r] = bf16(W[r][c]) ----------------
__global__ void __launch_bounds__(256) transpose_to_bf16(
    const float* __restrict__ W, unsigned short* __restrict__ Wt, int R, int C)
{
    __shared__ float t[32][33];
    int tid = threadIdx.x;
    int tr = tid >> 5, tc = tid & 31;
    int r0 = blockIdx.y * 32, c0 = blockIdx.x * 32;
    #pragma unroll
    for (int p = 0; p < 4; p++)
        t[tr + p * 8][tc] = W[(size_t)(r0 + tr + p * 8) * C + c0 + tc];
    __syncthreads();
    #pragma unroll
    for (int p = 0; p < 4; p++)
        Wt[(size_t)(c0 + tr + p * 8) * R + r0 + tc] = f2bf(t[tc][tr + p * 8]);
}

// ---------------- LN over 512 (input) -> bf16 nx; also bf16 raw x into A2 ----------------
__global__ void __launch_bounds__(256) ln512_kernel(
    const float* __restrict__ x, const float* __restrict__ w,
    const float* __restrict__ b,
    unsigned short* __restrict__ nxb, unsigned short* __restrict__ A2)
{
    int row = blockIdx.x;
    int tid = threadIdx.x;
    const float* xr = x + (size_t)row * 512;
    float2 v = *(const float2*)(xr + tid * 2);
    float s = v.x + v.y;
    float sq = v.x * v.x + v.y * v.y;
    for (int o = 32; o > 0; o >>= 1) { s += __shfl_down(s, o); sq += __shfl_down(sq, o); }
    __shared__ float red[8];
    int wv = tid >> 6;
    if ((tid & 63) == 0) { red[wv] = s; red[4 + wv] = sq; }
    __syncthreads();
    float ts = red[0] + red[1] + red[2] + red[3];
    float tq = red[4] + red[5] + red[6] + red[7];
    float mu = ts * (1.f / 512.f);
    float var = tq * (1.f / 512.f) - mu * mu;
    float rs = rsqrtf(var + 1e-6f);
    float2 wv2 = *(const float2*)(w + tid * 2);
    float2 bv  = *(const float2*)(b + tid * 2);
    ushort2 hn, hx;
    hn.x = f2bf((v.x - mu) * rs * wv2.x + bv.x);
    hn.y = f2bf((v.y - mu) * rs * wv2.y + bv.y);
    hx.x = f2bf(v.x);
    hx.y = f2bf(v.y);
    *(ushort2*)(nxb + (size_t)row * 512 + tid * 2) = hn;
    *(ushort2*)(A2 + (size_t)row * 1024 + 256 + tid * 2) = hx;
}

// ---------------- LN over 256 (output) -> bf16 y into A2 ----------------
__global__ void __launch_bounds__(256) ln256_kernel(
    const float* __restrict__ a, const float* __restrict__ w,
    const float* __restrict__ b, unsigned short* __restrict__ A2)
{
    int row = blockIdx.x;
    int tid = threadIdx.x;
    float v = a[(size_t)row * 256 + tid];
    float s = v, sq = v * v;
    for (int o = 32; o > 0; o >>= 1) { s += __shfl_down(s, o); sq += __shfl_down(sq, o); }
    __shared__ float red[8];
    int wv = tid >> 6;
    if ((tid & 63) == 0) { red[wv] = s; red[4 + wv] = sq; }
    __syncthreads();
    float ts = red[0] + red[1] + red[2] + red[3];
    float tq = red[4] + red[5] + red[6] + red[7];
    float mu = ts * (1.f / 256.f);
    float var = tq * (1.f / 256.f) - mu * mu;
    float rs = rsqrtf(var + 1e-6f);
    A2[(size_t)row * 1024 + 768 + tid] = f2bf((v - mu) * rs * w[tid] + b[tid]);
}

// ---------------- GEMM1 (MFMA bf16): silu(nx @ W1 + b) -> A2 u-cols + qkvb ----------------
__global__ void __launch_bounds__(256) gemm1_mfma(
    const unsigned short* __restrict__ Ab, const unsigned short* __restrict__ Bt,
    const float* __restrict__ bias,
    unsigned short* __restrict__ A2, unsigned short* __restrict__ qkvb)
{
    __shared__ unsigned short As[128 * PIT];
    __shared__ unsigned short Bs[128 * PIT];
    int tid = threadIdx.x;
    int lane = tid & 63, w = tid >> 6;
    int wr = w >> 1, wc = w & 1;
    int nn = lane & 15, qd = lane >> 4;
    int bm = blockIdx.y * 128, bn = blockIdx.x * 128;
    int srow = tid >> 3, scol = (tid & 7) * 8;

    f32x4 acc[4][4];
    #pragma unroll
    for (int i = 0; i < 4; i++)
        #pragma unroll
        for (int j = 0; j < 4; j++) acc[i][j] = (f32x4){0.f, 0.f, 0.f, 0.f};

    for (int k0 = 0; k0 < 512; k0 += 64) {
        __syncthreads();
        #pragma unroll
        for (int p = 0; p < 4; p++) {
            int r = srow + p * 32;
            *(short8*)&As[r * PIT + scol] = *(const short8*)(Ab + (size_t)(bm + r) * 512 + k0 + scol);
            *(short8*)&Bs[r * PIT + scol] = *(const short8*)(Bt + (size_t)(bn + r) * 512 + k0 + scol);
        }
        __syncthreads();
        #pragma unroll
        for (int kk = 0; kk < 2; kk++) {
            short8 af[4], bf[4];
            #pragma unroll
            for (int i = 0; i < 4; i++)
                af[i] = *(const short8*)&As[(wr * 64 + i * 16 + nn) * PIT + kk * 32 + qd * 8];
            #pragma unroll
            for (int j = 0; j < 4; j++)
                bf[j] = *(const short8*)&Bs[(wc * 64 + j * 16 + nn) * PIT + kk * 32 + qd * 8];
            #pragma unroll
            for (int i = 0; i < 4; i++)
                #pragma unroll
                for (int j = 0; j < 4; j++)
                    acc[i][j] = __builtin_amdgcn_mfma_f32_16x16x32_bf16(af[i], bf[j], acc[i][j], 0, 0, 0);
        }
    }
    #pragma unroll
    for (int j = 0; j < 4; j++) {
        int col = bn + wc * 64 + j * 16 + nn;
        float bb = bias[col];
        #pragma unroll
        for (int i = 0; i < 4; i++) {
            int rbase = bm + wr * 64 + i * 16 + qd * 4;
            #pragma unroll
            for (int r = 0; r < 4; r++) {
                unsigned short h = f2bf(silu_f(acc[i][j][r] + bb));
                if (col < 256) A2[(size_t)(rbase + r) * 1024 + col] = h;
                else           qkvb[(size_t)(rbase + r) * 768 + col - 256] = h;
            }
        }
    }
}

// ---------------- GEMM2 (MFMA bf16): out = x + A2 @ Wo ----------------
__global__ void __launch_bounds__(256) gemm2_mfma(
    const unsigned short* __restrict__ Ab, const unsigned short* __restrict__ Bt,
    const float* __restrict__ x, float* __restrict__ out)
{
    __shared__ unsigned short As[128 * PIT];
    __shared__ unsigned short Bs[128 * PIT];
    int tid = threadIdx.x;
    int lane = tid & 63, w = tid >> 6;
    int wr = w >> 1, wc = w & 1;
    int nn = lane & 15, qd = lane >> 4;
    int bm = blockIdx.y * 128, bn = blockIdx.x * 128;
    int srow = tid >> 3, scol = (tid & 7) * 8;

    f32x4 acc[4][4];
    #pragma unroll
    for (int i = 0; i < 4; i++)
        #pragma unroll
        for (int j = 0; j < 4; j++) acc[i][j] = (f32x4){0.f, 0.f, 0.f, 0.f};

    for (int k0 = 0; k0 < 1024; k0 += 64) {
        __syncthreads();
        #pragma unroll
        for (int p = 0; p < 4; p++) {
            int r = srow + p * 32;
            *(short8*)&As[r * PIT + scol] = *(const short8*)(Ab + (size_t)(bm + r) * 1024 + k0 + scol);
            *(short8*)&Bs[r * PIT + scol] = *(const short8*)(Bt + (size_t)(bn + r) * 1024 + k0 + scol);
        }
        __syncthreads();
        #pragma unroll
        for (int kk = 0; kk < 2; kk++) {
            short8 af[4], bf[4];
            #pragma unroll
            for (int i = 0; i < 4; i++)
                af[i] = *(const short8*)&As[(wr * 64 + i * 16 + nn) * PIT + kk * 32 + qd * 8];
            #pragma unroll
            for (int j = 0; j < 4; j++)
                bf[j] = *(const short8*)&Bs[(wc * 64 + j * 16 + nn) * PIT + kk * 32 + qd * 8];
            #pragma unroll
            for (int i = 0; i < 4; i++)
                #pragma unroll
                for (int j = 0; j < 4; j++)
                    acc[i][j] = __builtin_amdgcn_mfma_f32_16x16x32_bf16(af[i], bf[j], acc[i][j], 0, 0, 0);
        }
    }
    #pragma unroll
    for (int j = 0; j < 4; j++) {
        int col = bn + wc * 64 + j * 16 + nn;
        #pragma unroll
        for (int i = 0; i < 4; i++) {
            int rbase = bm + wr * 64 + i * 16 + qd * 4;
            #pragma unroll
            for (int r = 0; r < 4; r++) {
                size_t idx = (size_t)(rbase + r) * 512 + col;
                out[idx] = x[idx] + acc[i][j][r];
            }
        }
    }
}

// ---------------- Attention (MFMA bf16, split-m, S^T + register-P PV) ----------------
// grid: (8 splits, N/64, H*B). Split s handles m in [s*256, s*256+256).
// S^T = K Q^T (A=K from LDS, B=Q regs) -> P^T C-layout == B-frag of 16x16x16 mfma
// -> O^T = V^T P^T with V^T A-frags from LDS. No Ps round-trip, 1 barrier pair/chunk,
// next chunk's K/V prefetched into registers while current chunk computes.
__global__ void __launch_bounds__(256) attn_mfma_kernel(
    const unsigned short* __restrict__ qkvb,
    const int* __restrict__ offsets,
    const int* __restrict__ lengths,
    const int* __restrict__ num_targets,
    float* __restrict__ attn)
{
    int bh = blockIdx.z;
    int b = bh >> 2, h = bh & 3;
    int len = lengths[b];
    int n0 = (int)blockIdx.y * 64;
    if (n0 >= len) return;
    int m_hi = min(n0 + 63, len - 1);
    int s0 = (int)blockIdx.x;
    int m_start = s0 * 256;
    if (m_start > m_hi) return;
    int m_stop = min(m_start + 256, m_hi + 1);

    int off = offsets[b];
    int max_id = len - num_targets[b];
    int tid = threadIdx.x;
    int lane = tid & 63;
    int w = tid >> 6;
    int nn = lane & 15;
    int qd = lane >> 4;

    __shared__ unsigned short Ks[64 * PIT];
    __shared__ unsigned short Vt[64 * PIT];
#if !HAS_MFMA16
    __shared__ unsigned short Ps[64 * PIT];
#endif

    // Q B-frags in registers (col n = n0+w*16+nn, k = qd*8+j)
    int qrow = min(n0 + w * 16 + nn, len - 1);
    const unsigned short* qbase = qkvb + (size_t)(off + qrow) * 768 + 256 + h * 64;
    short8 qf0 = *(const short8*)(qbase + qd * 8);
    short8 qf1 = *(const short8*)(qbase + 32 + qd * 8);

    f32x4 o_acc[4];
    #pragma unroll
    for (int t = 0; t < 4; t++) o_acc[t] = (f32x4){0.f, 0.f, 0.f, 0.f};

    const float alpha = 0.125f;
    int idn = min(n0 + w * 16 + nn, max_id);   // per-lane n id (direct path)
    int nctx = n0 + w * 16 + nn;

    // staging indices
    int ks_row = tid >> 2, ks_c0 = (tid & 3) * 16;
    int vt_m = (tid & 31) * 2, vt_d0 = (tid >> 5) * 8;

    // --- prefetch chunk m_start into registers ---
    short8 kr0 = {0,0,0,0,0,0,0,0}, kr1 = {0,0,0,0,0,0,0,0};
    short8 vr0 = {0,0,0,0,0,0,0,0}, vr1 = {0,0,0,0,0,0,0,0};
    {
        int mendc = min(m_start + 64, len);
        int mg = m_start + ks_row;
        if (mg < mendc) {
            const unsigned short* kb = qkvb + (size_t)(off + mg) * 768 + 512 + h * 64 + ks_c0;
            kr0 = *(const short8*)kb;
            kr1 = *(const short8*)(kb + 8);
        }
        int mgA = m_start + vt_m, mgB = mgA + 1;
        if (mgA < mendc) vr0 = *(const short8*)(qkvb + (size_t)(off + mgA) * 768 + h * 64 + vt_d0);
        if (mgB < mendc) vr1 = *(const short8*)(qkvb + (size_t)(off + mgB) * 768 + h * 64 + vt_d0);
    }

    for (int m0 = m_start; m0 < m_stop; m0 += 64) {
        __syncthreads();   // prev chunk's LDS reads done
        // --- publish prefetched K (row-major) and V (transposed) ---
        *(short8*)&Ks[ks_row * PIT + ks_c0]     = kr0;
        *(short8*)&Ks[ks_row * PIT + ks_c0 + 8] = kr1;
        #pragma unroll
        for (int i = 0; i < 8; i++) {
            unsigned int pk = (unsigned int)(unsigned short)vr0[i] |
                              ((unsigned int)(unsigned short)vr1[i] << 16);
            *(unsigned int*)&Vt[(vt_d0 + i) * PIT + vt_m] = pk;
        }
        __syncthreads();
        // --- prefetch next chunk while computing this one ---
        int m1 = m0 + 64;
        if (m1 < m_stop) {
            int mendc = min(m1 + 64, len);
            int mg = m1 + ks_row;
            kr0 = (short8){0,0,0,0,0,0,0,0}; kr1 = (short8){0,0,0,0,0,0,0,0};
            vr0 = (short8){0,0,0,0,0,0,0,0}; vr1 = (short8){0,0,0,0,0,0,0,0};
            if (mg < mendc) {
                const unsigned short* kb = qkvb + (size_t)(off + mg) * 768 + 512 + h * 64 + ks_c0;
                kr0 = *(const short8*)kb;
                kr1 = *(const short8*)(kb + 8);
            }
            int mgA = m1 + vt_m, mgB = mgA + 1;
            if (mgA < mendc) vr0 = *(const short8*)(qkvb + (size_t)(off + mgA) * 768 + h * 64 + vt_d0);
            if (mgB < mendc) vr1 = *(const short8*)(qkvb + (size_t)(off + mgB) * 768 + h * 64 + vt_d0);
        }
        // --- S^T = K Q^T : 4 m-subtiles; lane holds S^T[m=s*16+qd*4+r][n=nn] ---
        #pragma unroll
        for (int s = 0; s < 4; s++) {
            f32x4 st = (f32x4){0.f, 0.f, 0.f, 0.f};
            short8 kf0 = *(const short8*)&Ks[(s * 16 + nn) * PIT + qd * 8];
            short8 kf1 = *(const short8*)&Ks[(s * 16 + nn) * PIT + 32 + qd * 8];
            st = __builtin_amdgcn_mfma_f32_16x16x32_bf16(kf0, qf0, st, 0, 0, 0);
            st = __builtin_amdgcn_mfma_f32_16x16x32_bf16(kf1, qf1, st, 0, 0, 0);
            // mask + silu in registers
            float p[4];
            #pragma unroll
            for (int r = 0; r < 4; r++) {
                int mcol = m0 + s * 16 + qd * 4 + r;
                int idm = min(mcol, max_id);
                bool ok = (idm < idn) || (mcol == nctx);
                p[r] = ok ? silu_f(st[r] * alpha) : 0.f;
            }
#if HAS_MFMA16
            short4v bop;
            bop[0] = (short)f2bf(p[0]); bop[1] = (short)f2bf(p[1]);
            bop[2] = (short)f2bf(p[2]); bop[3] = (short)f2bf(p[3]);
            // O^T += V^T[.][m-subtile s] * P^T[s][.]
            #pragma unroll
            for (int t = 0; t < 4; t++) {
                short4v aop = *(const short4v*)&Vt[(t * 16 + nn) * PIT + s * 16 + qd * 4];
                o_acc[t] = __builtin_amdgcn_mfma_f32_16x16x16bf16_1k(aop, bop, o_acc[t], 0, 0, 0);
            }
#else
            // fallback: P -> LDS (wave-local rows; no barrier needed)
            #pragma unroll
            for (int r = 0; r < 4; r++)
                Ps[(w * 16 + nn) * PIT + s * 16 + qd * 4 + r] = f2bf(p[r]);
#endif
        }
#if !HAS_MFMA16
        {
            short8 pf0 = *(const short8*)&Ps[(w * 16 + nn) * PIT + qd * 8];
            short8 pf1 = *(const short8*)&Ps[(w * 16 + nn) * PIT + 32 + qd * 8];
            #pragma unroll
            for (int t = 0; t < 4; t++) {
                short8 vf0 = *(const short8*)&Vt[(t * 16 + nn) * PIT + qd * 8];
                short8 vf1 = *(const short8*)&Vt[(t * 16 + nn) * PIT + 32 + qd * 8];
                o_acc[t] = __builtin_amdgcn_mfma_f32_16x16x32_bf16(pf0, vf0, o_acc[t], 0, 0, 0);
                o_acc[t] = __builtin_amdgcn_mfma_f32_16x16x32_bf16(pf1, vf1, o_acc[t], 0, 0, 0);
            }
        }
#endif
    }
    const float invN = 1.f / (float)NSEQ;
#if HAS_MFMA16
    // O^T C-layout: lane holds O^T[v=t*16+qd*4+r][n=n0+w*16+nn]
    if (nctx < len) {
        float* dst = attn + (size_t)(off + nctx) * 256 + h * 64;
        #pragma unroll
        for (int t = 0; t < 4; t++)
            #pragma unroll
            for (int r = 0; r < 4; r++)
                atomicAdd(dst + t * 16 + qd * 4 + r, o_acc[t][r] * invN);
    }
#else
    // O C-layout: lane holds O[n=n0+w*16+qd*4+r][v=t*16+nn]
    #pragma unroll
    for (int r = 0; r < 4; r++) {
        int n = n0 + w * 16 + qd * 4 + r;
        if (n < len) {
            float* dst = attn + (size_t)(off + n) * 256 + h * 64 + nn;
            #pragma unroll
            for (int t = 0; t < 4; t++)
                atomicAdd(dst + t * 16, o_acc[t][r] * invN);
        }
    }
#endif
}

extern "C" void kernel_launch(void* const* d_in, const int* in_sizes, int n_in,
                              void* d_out, int out_size, void* d_ws, size_t ws_size,
                              hipStream_t stream)
{
    const float* x          = (const float*)d_in[0];
    const int*   x_lengths  = (const int*)d_in[1];
    const int*   x_offsets  = (const int*)d_in[2];
    // d_in[3] = max_seq_len (2048, hardcoded as NSEQ)
    const int*   num_targets = (const int*)d_in[4];
    const float* uvqk_w     = (const float*)d_in[5];
    const float* uvqk_b     = (const float*)d_in[6];
    const float* in_w       = (const float*)d_in[7];
    const float* in_b       = (const float*)d_in[8];
    const float* out_w      = (const float*)d_in[9];
    const float* out_b      = (const float*)d_in[10];
    const float* Wo         = (const float*)d_in[11];
    float* out = (float*)d_out;

    int L = in_sizes[0] / 512;   // 6400
    int B = in_sizes[1];         // 4

    char* ws = (char*)d_ws;
    size_t o = 0;
    float* attn = (float*)(ws + o);          o += (size_t)L * 256 * 4;   // fp32 attn
    unsigned short* nxb  = (unsigned short*)(ws + o); o += (size_t)L * 512 * 2;
    unsigned short* A2   = (unsigned short*)(ws + o); o += (size_t)L * 1024 * 2;
    unsigned short* qkvb = (unsigned short*)(ws + o); o += (size_t)L * 768 * 2;
    unsigned short* W1t  = (unsigned short*)(ws + o); o += (size_t)1024 * 512 * 2;
    unsigned short* W2t  = (unsigned short*)(ws + o); o += (size_t)512 * 1024 * 2;

    // zero attn accumulator (split-m atomics add into it)
    hipMemsetAsync(attn, 0, (size_t)L * 256 * 4, stream);

    // 0) weight transpose + cast (per-launch; ~3 MB)
    transpose_to_bf16<<<dim3(1024 / 32, 512 / 32), 256, 0, stream>>>(uvqk_w, W1t, 512, 1024);
    transpose_to_bf16<<<dim3(512 / 32, 1024 / 32), 256, 0, stream>>>(Wo, W2t, 1024, 512);

    // 1) input LN -> bf16 nx; raw x -> bf16 A2[:,256:768)
    ln512_kernel<<<L, 256, 0, stream>>>(x, in_w, in_b, nxb, A2);

    // 2) uvqk = silu(nx @ W1 + b): u -> A2[:,0:256), v/q/k -> qkvb
    dim3 g1(1024 / 128, L / 128);
    gemm1_mfma<<<g1, 256, 0, stream>>>(nxb, W1t, uvqk_b, A2, qkvb);

    // 3) attention (MFMA bf16, split-m, S^T formulation)
    dim3 g2(8, NSEQ / 64, 16);
    attn_mfma_kernel<<<g2, 256, 0, stream>>>(qkvb, x_offsets, x_lengths, num_targets, attn);

    // 4) output LN -> bf16 A2[:,768:1024)
    ln256_kernel<<<L, 256, 0, stream>>>(attn, out_w, out_b, A2);

    // 5) out = x + A2 @ Wo
    dim3 g3(512 / 128, L / 128);
    gemm2_mfma<<<g3, 256, 0, stream>>>(A2, W2t, x, out);
}

// Round 6
// 189.066 us; speedup vs baseline: 1.2447x; 1.2447x over previous
//
#include <hip/hip_runtime.h>
#include <math.h>

// Problem constants (fixed by setup_inputs):
//   B=4, N=2048, D=512, H=4, A=64, V=64, L=6400
//   qkvb (bf16, L x 768): [0:256)=v, [256:512)=q, [512:768)=k
//   A2   (bf16, L x 1024): [0:256)=u, [256:768)=x, [768:1024)=y
#define NSEQ 2048
#define PIT 72   // LDS row pitch (bf16 elems): 144B rows -> 16B aligned, 2-way banks only

#if defined(__has_builtin)
#if __has_builtin(__builtin_amdgcn_mfma_f32_16x16x16bf16_1k)
#define HAS_MFMA16 1
#endif
#endif
#ifndef HAS_MFMA16
#define HAS_MFMA16 0
#endif

typedef __attribute__((ext_vector_type(8))) short short8;   // 8 bf16 = 4 VGPR
typedef __attribute__((ext_vector_type(4))) short short4v;  // 4 bf16 = 2 VGPR
typedef __attribute__((ext_vector_type(4))) float f32x4;    // MFMA acc

__device__ __forceinline__ float silu_f(float z) {
    return z / (1.f + __expf(-z));
}

__device__ __forceinline__ unsigned short f2bf(float f) {
    unsigned int u = __float_as_uint(f);
    u += 0x7fffu + ((u >> 16) & 1u);   // RNE (finite inputs only)
    return (unsigned short)(u >> 16);
}

__device__ __forceinline__ unsigned short f2bf_fast(float f) {
    // round-half-away; cheap (2 ops). Used on P only.
    return (unsigned short)((__float_as_uint(f) + 0x8000u) >> 16);
}

// exact for power-of-2 scale: bf16 -> f32 -> *s -> truncate back (mantissa unchanged)
__device__ __forceinline__ short8 scale8_pow2(short8 v, float s) {
    short8 r;
    #pragma unroll
    for (int i = 0; i < 8; i++) {
        float f = __uint_as_float(((unsigned int)(unsigned short)v[i]) << 16) * s;
        r[i] = (short)(unsigned short)(__float_as_uint(f) >> 16);
    }
    return r;
}

// ---------------- transpose + cast: Wt[c][r] = bf16(W[r][c]) ----------------
__global__ void __launch_bounds__(256) transpose_to_bf16(
    const float* __restrict__ W, unsigned short* __restrict__ Wt, int R, int C)
{
    __shared__ float t[32][33];
    int tid = threadIdx.x;
    int tr = tid >> 5, tc = tid & 31;
    int r0 = blockIdx.y * 32, c0 = blockIdx.x * 32;
    #pragma unroll
    for (int p = 0; p < 4; p++)
        t[tr + p * 8][tc] = W[(size_t)(r0 + tr + p * 8) * C + c0 + tc];
    __syncthreads();
    #pragma unroll
    for (int p = 0; p < 4; p++)
        Wt[(size_t)(c0 + tr + p * 8) * R + r0 + tc] = f2bf(t[tc][tr + p * 8]);
}

// ---------------- LN over 512 (input) -> bf16 nx; also bf16 raw x into A2 ----------------
__global__ void __launch_bounds__(256) ln512_kernel(
    const float* __restrict__ x, const float* __restrict__ w,
    const float* __restrict__ b,
    unsigned short* __restrict__ nxb, unsigned short* __restrict__ A2)
{
    int row = blockIdx.x;
    int tid = threadIdx.x;
    const float* xr = x + (size_t)row * 512;
    float2 v = *(const float2*)(xr + tid * 2);
    float s = v.x + v.y;
    float sq = v.x * v.x + v.y * v.y;
    for (int o = 32; o > 0; o >>= 1) { s += __shfl_down(s, o); sq += __shfl_down(sq, o); }
    __shared__ float red[8];
    int wv = tid >> 6;
    if ((tid & 63) == 0) { red[wv] = s; red[4 + wv] = sq; }
    __syncthreads();
    float ts = red[0] + red[1] + red[2] + red[3];
    float tq = red[4] + red[5] + red[6] + red[7];
    float mu = ts * (1.f / 512.f);
    float var = tq * (1.f / 512.f) - mu * mu;
    float rs = rsqrtf(var + 1e-6f);
    float2 wv2 = *(const float2*)(w + tid * 2);
    float2 bv  = *(const float2*)(b + tid * 2);
    ushort2 hn, hx;
    hn.x = f2bf((v.x - mu) * rs * wv2.x + bv.x);
    hn.y = f2bf((v.y - mu) * rs * wv2.y + bv.y);
    hx.x = f2bf(v.x);
    hx.y = f2bf(v.y);
    *(ushort2*)(nxb + (size_t)row * 512 + tid * 2) = hn;
    *(ushort2*)(A2 + (size_t)row * 1024 + 256 + tid * 2) = hx;
}

// ---------------- LN over 256 (output) -> bf16 y into A2 ----------------
__global__ void __launch_bounds__(256) ln256_kernel(
    const float* __restrict__ a, const float* __restrict__ w,
    const float* __restrict__ b, unsigned short* __restrict__ A2)
{
    int row = blockIdx.x;
    int tid = threadIdx.x;
    float v = a[(size_t)row * 256 + tid];
    float s = v, sq = v * v;
    for (int o = 32; o > 0; o >>= 1) { s += __shfl_down(s, o); sq += __shfl_down(sq, o); }
    __shared__ float red[8];
    int wv = tid >> 6;
    if ((tid & 63) == 0) { red[wv] = s; red[4 + wv] = sq; }
    __syncthreads();
    float ts = red[0] + red[1] + red[2] + red[3];
    float tq = red[4] + red[5] + red[6] + red[7];
    float mu = ts * (1.f / 256.f);
    float var = tq * (1.f / 256.f) - mu * mu;
    float rs = rsqrtf(var + 1e-6f);
    A2[(size_t)row * 1024 + 768 + tid] = f2bf((v - mu) * rs * w[tid] + b[tid]);
}

// ---------------- GEMM1 (MFMA bf16): silu(nx @ W1 + b) -> A2 u-cols + qkvb ----------------
__global__ void __launch_bounds__(256) gemm1_mfma(
    const unsigned short* __restrict__ Ab, const unsigned short* __restrict__ Bt,
    const float* __restrict__ bias,
    unsigned short* __restrict__ A2, unsigned short* __restrict__ qkvb)
{
    __shared__ unsigned short As[128 * PIT];
    __shared__ unsigned short Bs[128 * PIT];
    int tid = threadIdx.x;
    int lane = tid & 63, w = tid >> 6;
    int wr = w >> 1, wc = w & 1;
    int nn = lane & 15, qd = lane >> 4;
    int bm = blockIdx.y * 128, bn = blockIdx.x * 128;
    int srow = tid >> 3, scol = (tid & 7) * 8;

    f32x4 acc[4][4];
    #pragma unroll
    for (int i = 0; i < 4; i++)
        #pragma unroll
        for (int j = 0; j < 4; j++) acc[i][j] = (f32x4){0.f, 0.f, 0.f, 0.f};

    for (int k0 = 0; k0 < 512; k0 += 64) {
        __syncthreads();
        #pragma unroll
        for (int p = 0; p < 4; p++) {
            int r = srow + p * 32;
            *(short8*)&As[r * PIT + scol] = *(const short8*)(Ab + (size_t)(bm + r) * 512 + k0 + scol);
            *(short8*)&Bs[r * PIT + scol] = *(const short8*)(Bt + (size_t)(bn + r) * 512 + k0 + scol);
        }
        __syncthreads();
        #pragma unroll
        for (int kk = 0; kk < 2; kk++) {
            short8 af[4], bf[4];
            #pragma unroll
            for (int i = 0; i < 4; i++)
                af[i] = *(const short8*)&As[(wr * 64 + i * 16 + nn) * PIT + kk * 32 + qd * 8];
            #pragma unroll
            for (int j = 0; j < 4; j++)
                bf[j] = *(const short8*)&Bs[(wc * 64 + j * 16 + nn) * PIT + kk * 32 + qd * 8];
            #pragma unroll
            for (int i = 0; i < 4; i++)
                #pragma unroll
                for (int j = 0; j < 4; j++)
                    acc[i][j] = __builtin_amdgcn_mfma_f32_16x16x32_bf16(af[i], bf[j], acc[i][j], 0, 0, 0);
        }
    }
    #pragma unroll
    for (int j = 0; j < 4; j++) {
        int col = bn + wc * 64 + j * 16 + nn;
        float bb = bias[col];
        #pragma unroll
        for (int i = 0; i < 4; i++) {
            int rbase = bm + wr * 64 + i * 16 + qd * 4;
            #pragma unroll
            for (int r = 0; r < 4; r++) {
                unsigned short h = f2bf(silu_f(acc[i][j][r] + bb));
                if (col < 256) A2[(size_t)(rbase + r) * 1024 + col] = h;
                else           qkvb[(size_t)(rbase + r) * 768 + col - 256] = h;
            }
        }
    }
}

// ---------------- GEMM2 (MFMA bf16): out = x + A2 @ Wo ----------------
__global__ void __launch_bounds__(256) gemm2_mfma(
    const unsigned short* __restrict__ Ab, const unsigned short* __restrict__ Bt,
    const float* __restrict__ x, float* __restrict__ out)
{
    __shared__ unsigned short As[128 * PIT];
    __shared__ unsigned short Bs[128 * PIT];
    int tid = threadIdx.x;
    int lane = tid & 63, w = tid >> 6;
    int wr = w >> 1, wc = w & 1;
    int nn = lane & 15, qd = lane >> 4;
    int bm = blockIdx.y * 128, bn = blockIdx.x * 128;
    int srow = tid >> 3, scol = (tid & 7) * 8;

    f32x4 acc[4][4];
    #pragma unroll
    for (int i = 0; i < 4; i++)
        #pragma unroll
        for (int j = 0; j < 4; j++) acc[i][j] = (f32x4){0.f, 0.f, 0.f, 0.f};

    for (int k0 = 0; k0 < 1024; k0 += 64) {
        __syncthreads();
        #pragma unroll
        for (int p = 0; p < 4; p++) {
            int r = srow + p * 32;
            *(short8*)&As[r * PIT + scol] = *(const short8*)(Ab + (size_t)(bm + r) * 1024 + k0 + scol);
            *(short8*)&Bs[r * PIT + scol] = *(const short8*)(Bt + (size_t)(bn + r) * 1024 + k0 + scol);
        }
        __syncthreads();
        #pragma unroll
        for (int kk = 0; kk < 2; kk++) {
            short8 af[4], bf[4];
            #pragma unroll
            for (int i = 0; i < 4; i++)
                af[i] = *(const short8*)&As[(wr * 64 + i * 16 + nn) * PIT + kk * 32 + qd * 8];
            #pragma unroll
            for (int j = 0; j < 4; j++)
                bf[j] = *(const short8*)&Bs[(wc * 64 + j * 16 + nn) * PIT + kk * 32 + qd * 8];
            #pragma unroll
            for (int i = 0; i < 4; i++)
                #pragma unroll
                for (int j = 0; j < 4; j++)
                    acc[i][j] = __builtin_amdgcn_mfma_f32_16x16x32_bf16(af[i], bf[j], acc[i][j], 0, 0, 0);
        }
    }
    #pragma unroll
    for (int j = 0; j < 4; j++) {
        int col = bn + wc * 64 + j * 16 + nn;
        #pragma unroll
        for (int i = 0; i < 4; i++) {
            int rbase = bm + wr * 64 + i * 16 + qd * 4;
            #pragma unroll
            for (int r = 0; r < 4; r++) {
                size_t idx = (size_t)(rbase + r) * 512 + col;
                out[idx] = x[idx] + acc[i][j][r];
            }
        }
    }
}

// ---------------- Attention (MFMA bf16, split-m, S^T + register-P PV) ----------------
// grid: (8 splits, N/64, H*B). Split s handles m in [s*256, s*256+256).
// S^T = K Q^T (alpha folded into Q); P^T stays in registers as the B-frag of
// 16x16x16 mfma; O^T = V^T P^T. Epilogue transposes O^T->O through LDS (overlay
// on Ks/Vt) so the split-m atomicAdds are row-coalesced (the round-5 scattered
// atomics quadrupled WRITE_SIZE and made the kernel HBM-write-bound).
__global__ void __launch_bounds__(256) attn_mfma_kernel(
    const unsigned short* __restrict__ qkvb,
    const int* __restrict__ offsets,
    const int* __restrict__ lengths,
    const int* __restrict__ num_targets,
    float* __restrict__ attn)
{
    int bh = blockIdx.z;
    int b = bh >> 2, h = bh & 3;
    int len = lengths[b];
    int n0 = (int)blockIdx.y * 64;
    if (n0 >= len) return;
    int m_hi = min(n0 + 63, len - 1);
    int s0 = (int)blockIdx.x;
    int m_start = s0 * 256;
    if (m_start > m_hi) return;
    int m_stop = min(m_start + 256, m_hi + 1);

    int off = offsets[b];
    int max_id = len - num_targets[b];
    int tid = threadIdx.x;
    int lane = tid & 63;
    int w = tid >> 6;
    int nn = lane & 15;
    int qd = lane >> 4;

    __shared__ __align__(16) char smem[18432];
    unsigned short* Ks = (unsigned short*)smem;            // 64*PIT shorts = 9216 B
    unsigned short* Vt = (unsigned short*)(smem + 9216);   // 9216 B
    float* Os = (float*)smem;                              // overlay after m-loop (64x65 f32)
#if !HAS_MFMA16
    __shared__ unsigned short Ps[64 * PIT];
#endif

    int nctx = n0 + w * 16 + nn;
    int idn = min(nctx, max_id);
    int fast_lim = min(n0, max_id);   // chunk fully unmasked iff m0+63 < fast_lim

    // Q B-frags in registers, pre-scaled by alpha=0.125 (exact pow2 scale)
    int qrow = min(nctx, len - 1);
    const unsigned short* qbase = qkvb + (size_t)(off + qrow) * 768 + 256 + h * 64;
    short8 qf0 = scale8_pow2(*(const short8*)(qbase + qd * 8), 0.125f);
    short8 qf1 = scale8_pow2(*(const short8*)(qbase + 32 + qd * 8), 0.125f);

    f32x4 o_acc[4];
    #pragma unroll
    for (int t = 0; t < 4; t++) o_acc[t] = (f32x4){0.f, 0.f, 0.f, 0.f};

    // staging indices
    int ks_row = tid >> 2, ks_c0 = (tid & 3) * 16;
    int vt_m = (tid & 31) * 2, vt_d0 = (tid >> 5) * 8;

    // --- prefetch chunk m_start into registers ---
    short8 kr0 = {0,0,0,0,0,0,0,0}, kr1 = {0,0,0,0,0,0,0,0};
    short8 vr0 = {0,0,0,0,0,0,0,0}, vr1 = {0,0,0,0,0,0,0,0};
    {
        int mendc = min(m_start + 64, len);
        int mg = m_start + ks_row;
        if (mg < mendc) {
            const unsigned short* kb = qkvb + (size_t)(off + mg) * 768 + 512 + h * 64 + ks_c0;
            kr0 = *(const short8*)kb;
            kr1 = *(const short8*)(kb + 8);
        }
        int mgA = m_start + vt_m, mgB = mgA + 1;
        if (mgA < mendc) vr0 = *(const short8*)(qkvb + (size_t)(off + mgA) * 768 + h * 64 + vt_d0);
        if (mgB < mendc) vr1 = *(const short8*)(qkvb + (size_t)(off + mgB) * 768 + h * 64 + vt_d0);
    }

    for (int m0 = m_start; m0 < m_stop; m0 += 64) {
        __syncthreads();   // prev chunk's LDS reads done
        *(short8*)&Ks[ks_row * PIT + ks_c0]     = kr0;
        *(short8*)&Ks[ks_row * PIT + ks_c0 + 8] = kr1;
        #pragma unroll
        for (int i = 0; i < 8; i++) {
            unsigned int pk = (unsigned int)(unsigned short)vr0[i] |
                              ((unsigned int)(unsigned short)vr1[i] << 16);
            *(unsigned int*)&Vt[(vt_d0 + i) * PIT + vt_m] = pk;
        }
        __syncthreads();
        // prefetch next chunk while computing this one
        int m1 = m0 + 64;
        if (m1 < m_stop) {
            int mendc = min(m1 + 64, len);
            int mg = m1 + ks_row;
            kr0 = (short8){0,0,0,0,0,0,0,0}; kr1 = (short8){0,0,0,0,0,0,0,0};
            vr0 = (short8){0,0,0,0,0,0,0,0}; vr1 = (short8){0,0,0,0,0,0,0,0};
            if (mg < mendc) {
                const unsigned short* kb = qkvb + (size_t)(off + mg) * 768 + 512 + h * 64 + ks_c0;
                kr0 = *(const short8*)kb;
                kr1 = *(const short8*)(kb + 8);
            }
            int mgA = m1 + vt_m, mgB = mgA + 1;
            if (mgA < mendc) vr0 = *(const short8*)(qkvb + (size_t)(off + mgA) * 768 + h * 64 + vt_d0);
            if (mgB < mendc) vr1 = *(const short8*)(qkvb + (size_t)(off + mgB) * 768 + h * 64 + vt_d0);
        }
        bool fastp = (m0 + 63 < fast_lim);   // wave-uniform: whole chunk passes the mask
        #pragma unroll
        for (int s = 0; s < 4; s++) {
            f32x4 st = (f32x4){0.f, 0.f, 0.f, 0.f};
            short8 kf0 = *(const short8*)&Ks[(s * 16 + nn) * PIT + qd * 8];
            short8 kf1 = *(const short8*)&Ks[(s * 16 + nn) * PIT + 32 + qd * 8];
            st = __builtin_amdgcn_mfma_f32_16x16x32_bf16(kf0, qf0, st, 0, 0, 0);
            st = __builtin_amdgcn_mfma_f32_16x16x32_bf16(kf1, qf1, st, 0, 0, 0);
            float p[4];
            if (fastp) {
                #pragma unroll
                for (int r = 0; r < 4; r++) p[r] = silu_f(st[r]);
            } else {
                #pragma unroll
                for (int r = 0; r < 4; r++) {
                    int mcol = m0 + s * 16 + qd * 4 + r;
                    // idn<=max_id  =>  min(m,max_id)<idn  <=>  m<idn
                    bool ok = (mcol < idn) || (mcol == nctx);
                    p[r] = ok ? silu_f(st[r]) : 0.f;
                }
            }
#if HAS_MFMA16
            short4v bop;
            bop[0] = (short)f2bf_fast(p[0]); bop[1] = (short)f2bf_fast(p[1]);
            bop[2] = (short)f2bf_fast(p[2]); bop[3] = (short)f2bf_fast(p[3]);
            #pragma unroll
            for (int t = 0; t < 4; t++) {
                short4v aop = *(const short4v*)&Vt[(t * 16 + nn) * PIT + s * 16 + qd * 4];
                o_acc[t] = __builtin_amdgcn_mfma_f32_16x16x16bf16_1k(aop, bop, o_acc[t], 0, 0, 0);
            }
#else
            #pragma unroll
            for (int r = 0; r < 4; r++)
                Ps[(w * 16 + nn) * PIT + s * 16 + qd * 4 + r] = f2bf_fast(p[r]);
#endif
        }
#if !HAS_MFMA16
        {
            short8 pf0 = *(const short8*)&Ps[(w * 16 + nn) * PIT + qd * 8];
            short8 pf1 = *(const short8*)&Ps[(w * 16 + nn) * PIT + 32 + qd * 8];
            #pragma unroll
            for (int t = 0; t < 4; t++) {
                short8 vf0 = *(const short8*)&Vt[(t * 16 + nn) * PIT + qd * 8];
                short8 vf1 = *(const short8*)&Vt[(t * 16 + nn) * PIT + 32 + qd * 8];
                o_acc[t] = __builtin_amdgcn_mfma_f32_16x16x32_bf16(pf0, vf0, o_acc[t], 0, 0, 0);
                o_acc[t] = __builtin_amdgcn_mfma_f32_16x16x32_bf16(pf1, vf1, o_acc[t], 0, 0, 0);
            }
        }
#endif
    }
    const float invN = 1.f / (float)NSEQ;
#if HAS_MFMA16
    // transpose O^T -> O through LDS overlay so global atomics are row-coalesced
    __syncthreads();   // all waves done reading Ks/Vt
    #pragma unroll
    for (int t = 0; t < 4; t++)
        #pragma unroll
        for (int r = 0; r < 4; r++)
            Os[(w * 16 + nn) * 65 + t * 16 + qd * 4 + r] = o_acc[t][r] * invN;
    __syncthreads();
    #pragma unroll
    for (int r = 0; r < 4; r++) {
        int n = n0 + w * 16 + qd * 4 + r;
        if (n < len) {
            float* dst = attn + (size_t)(off + n) * 256 + h * 64 + nn;
            #pragma unroll
            for (int t = 0; t < 4; t++)
                atomicAdd(dst + t * 16, Os[(w * 16 + qd * 4 + r) * 65 + t * 16 + nn]);
        }
    }
#else
    #pragma unroll
    for (int r = 0; r < 4; r++) {
        int n = n0 + w * 16 + qd * 4 + r;
        if (n < len) {
            float* dst = attn + (size_t)(off + n) * 256 + h * 64 + nn;
            #pragma unroll
            for (int t = 0; t < 4; t++)
                atomicAdd(dst + t * 16, o_acc[t][r] * invN);
        }
    }
#endif
}

extern "C" void kernel_launch(void* const* d_in, const int* in_sizes, int n_in,
                              void* d_out, int out_size, void* d_ws, size_t ws_size,
                              hipStream_t stream)
{
    const float* x          = (const float*)d_in[0];
    const int*   x_lengths  = (const int*)d_in[1];
    const int*   x_offsets  = (const int*)d_in[2];
    // d_in[3] = max_seq_len (2048, hardcoded as NSEQ)
    const int*   num_targets = (const int*)d_in[4];
    const float* uvqk_w     = (const float*)d_in[5];
    const float* uvqk_b     = (const float*)d_in[6];
    const float* in_w       = (const float*)d_in[7];
    const float* in_b       = (const float*)d_in[8];
    const float* out_w      = (const float*)d_in[9];
    const float* out_b      = (const float*)d_in[10];
    const float* Wo         = (const float*)d_in[11];
    float* out = (float*)d_out;

    int L = in_sizes[0] / 512;   // 6400
    int B = in_sizes[1];         // 4

    char* ws = (char*)d_ws;
    size_t o = 0;
    float* attn = (float*)(ws + o);          o += (size_t)L * 256 * 4;   // fp32 attn
    unsigned short* nxb  = (unsigned short*)(ws + o); o += (size_t)L * 512 * 2;
    unsigned short* A2   = (unsigned short*)(ws + o); o += (size_t)L * 1024 * 2;
    unsigned short* qkvb = (unsigned short*)(ws + o); o += (size_t)L * 768 * 2;
    unsigned short* W1t  = (unsigned short*)(ws + o); o += (size_t)1024 * 512 * 2;
    unsigned short* W2t  = (unsigned short*)(ws + o); o += (size_t)512 * 1024 * 2;

    // zero attn accumulator (split-m atomics add into it)
    hipMemsetAsync(attn, 0, (size_t)L * 256 * 4, stream);

    // 0) weight transpose + cast (per-launch; ~3 MB)
    transpose_to_bf16<<<dim3(1024 / 32, 512 / 32), 256, 0, stream>>>(uvqk_w, W1t, 512, 1024);
    transpose_to_bf16<<<dim3(512 / 32, 1024 / 32), 256, 0, stream>>>(Wo, W2t, 1024, 512);

    // 1) input LN -> bf16 nx; raw x -> bf16 A2[:,256:768)
    ln512_kernel<<<L, 256, 0, stream>>>(x, in_w, in_b, nxb, A2);

    // 2) uvqk = silu(nx @ W1 + b): u -> A2[:,0:256), v/q/k -> qkvb
    dim3 g1(1024 / 128, L / 128);
    gemm1_mfma<<<g1, 256, 0, stream>>>(nxb, W1t, uvqk_b, A2, qkvb);

    // 3) attention (MFMA bf16, split-m, S^T formulation, coalesced epilogue)
    dim3 g2(8, NSEQ / 64, 16);
    attn_mfma_kernel<<<g2, 256, 0, stream>>>(qkvb, x_offsets, x_lengths, num_targets, attn);

    // 4) output LN -> bf16 A2[:,768:1024)
    ln256_kernel<<<L, 256, 0, stream>>>(attn, out_w, out_b, A2);

    // 5) out = x + A2 @ Wo
    dim3 g3(512 / 128, L / 128);
    gemm2_mfma<<<g3, 256, 0, stream>>>(A2, W2t, x, out);
}

// Round 7
// 188.823 us; speedup vs baseline: 1.2463x; 1.0013x over previous
//
#include <hip/hip_runtime.h>
#include <math.h>

// Problem constants (fixed by setup_inputs):
//   B=4, N=2048, D=512, H=4, A=64, V=64, L=6400
//   qkvb (bf16, L x 768): [0:256)=v, [256:512)=q, [512:768)=k
//   A2   (bf16, L x 1024): [0:256)=u, [256:768)=x, [768:1024)=y
#define NSEQ 2048
#define PIT 72   // LDS row pitch (bf16 elems)

typedef __attribute__((ext_vector_type(8))) short short8;   // 8 bf16 = 4 VGPR
typedef __attribute__((ext_vector_type(4))) short short4v;  // 4 bf16 = 2 VGPR
typedef __attribute__((ext_vector_type(4))) float f32x4;    // MFMA acc

__device__ __forceinline__ float silu_f(float z) {
    return z / (1.f + __expf(-z));
}

__device__ __forceinline__ unsigned short f2bf(float f) {
    unsigned int u = __float_as_uint(f);
    u += 0x7fffu + ((u >> 16) & 1u);   // RNE (finite inputs only)
    return (unsigned short)(u >> 16);
}

__device__ __forceinline__ unsigned short f2bf_fast(float f) {
    return (unsigned short)((__float_as_uint(f) + 0x8000u) >> 16);
}

// exact for power-of-2 scale
__device__ __forceinline__ short8 scale8_pow2(short8 v, float s) {
    short8 r;
    #pragma unroll
    for (int i = 0; i < 8; i++) {
        float f = __uint_as_float(((unsigned int)(unsigned short)v[i]) << 16) * s;
        r[i] = (short)(unsigned short)(__float_as_uint(f) >> 16);
    }
    return r;
}

// ---------------- transpose + cast: Wt[c][r] = bf16(W[r][c]) ----------------
__global__ void __launch_bounds__(256) transpose_to_bf16(
    const float* __restrict__ W, unsigned short* __restrict__ Wt, int R, int C)
{
    __shared__ float t[32][33];
    int tid = threadIdx.x;
    int tr = tid >> 5, tc = tid & 31;
    int r0 = blockIdx.y * 32, c0 = blockIdx.x * 32;
    #pragma unroll
    for (int p = 0; p < 4; p++)
        t[tr + p * 8][tc] = W[(size_t)(r0 + tr + p * 8) * C + c0 + tc];
    __syncthreads();
    #pragma unroll
    for (int p = 0; p < 4; p++)
        Wt[(size_t)(c0 + tr + p * 8) * R + r0 + tc] = f2bf(t[tc][tr + p * 8]);
}

// ---------------- LN over 512 (input) -> bf16 nx; also bf16 raw x into A2 ----------------
__global__ void __launch_bounds__(256) ln512_kernel(
    const float* __restrict__ x, const float* __restrict__ w,
    const float* __restrict__ b,
    unsigned short* __restrict__ nxb, unsigned short* __restrict__ A2)
{
    int row = blockIdx.x;
    int tid = threadIdx.x;
    const float* xr = x + (size_t)row * 512;
    float2 v = *(const float2*)(xr + tid * 2);
    float s = v.x + v.y;
    float sq = v.x * v.x + v.y * v.y;
    for (int o = 32; o > 0; o >>= 1) { s += __shfl_down(s, o); sq += __shfl_down(sq, o); }
    __shared__ float red[8];
    int wv = tid >> 6;
    if ((tid & 63) == 0) { red[wv] = s; red[4 + wv] = sq; }
    __syncthreads();
    float ts = red[0] + red[1] + red[2] + red[3];
    float tq = red[4] + red[5] + red[6] + red[7];
    float mu = ts * (1.f / 512.f);
    float var = tq * (1.f / 512.f) - mu * mu;
    float rs = rsqrtf(var + 1e-6f);
    float2 wv2 = *(const float2*)(w + tid * 2);
    float2 bv  = *(const float2*)(b + tid * 2);
    ushort2 hn, hx;
    hn.x = f2bf((v.x - mu) * rs * wv2.x + bv.x);
    hn.y = f2bf((v.y - mu) * rs * wv2.y + bv.y);
    hx.x = f2bf(v.x);
    hx.y = f2bf(v.y);
    *(ushort2*)(nxb + (size_t)row * 512 + tid * 2) = hn;
    *(ushort2*)(A2 + (size_t)row * 1024 + 256 + tid * 2) = hx;
}

// ---------------- LN over 256 (output) -> bf16 y into A2 ----------------
__global__ void __launch_bounds__(256) ln256_kernel(
    const float* __restrict__ a, const float* __restrict__ w,
    const float* __restrict__ b, unsigned short* __restrict__ A2)
{
    int row = blockIdx.x;
    int tid = threadIdx.x;
    float v = a[(size_t)row * 256 + tid];
    float s = v, sq = v * v;
    for (int o = 32; o > 0; o >>= 1) { s += __shfl_down(s, o); sq += __shfl_down(sq, o); }
    __shared__ float red[8];
    int wv = tid >> 6;
    if ((tid & 63) == 0) { red[wv] = s; red[4 + wv] = sq; }
    __syncthreads();
    float ts = red[0] + red[1] + red[2] + red[3];
    float tq = red[4] + red[5] + red[6] + red[7];
    float mu = ts * (1.f / 256.f);
    float var = tq * (1.f / 256.f) - mu * mu;
    float rs = rsqrtf(var + 1e-6f);
    A2[(size_t)row * 1024 + 768 + tid] = f2bf((v - mu) * rs * w[tid] + b[tid]);
}

// ---------------- GEMM1 (MFMA bf16): silu(nx @ W1 + b) -> A2 u-cols + qkvb ----------------
__global__ void __launch_bounds__(256) gemm1_mfma(
    const unsigned short* __restrict__ Ab, const unsigned short* __restrict__ Bt,
    const float* __restrict__ bias,
    unsigned short* __restrict__ A2, unsigned short* __restrict__ qkvb)
{
    __shared__ unsigned short As[128 * PIT];
    __shared__ unsigned short Bs[128 * PIT];
    int tid = threadIdx.x;
    int lane = tid & 63, w = tid >> 6;
    int wr = w >> 1, wc = w & 1;
    int nn = lane & 15, qd = lane >> 4;
    int bm = blockIdx.y * 128, bn = blockIdx.x * 128;
    int srow = tid >> 3, scol = (tid & 7) * 8;

    f32x4 acc[4][4];
    #pragma unroll
    for (int i = 0; i < 4; i++)
        #pragma unroll
        for (int j = 0; j < 4; j++) acc[i][j] = (f32x4){0.f, 0.f, 0.f, 0.f};

    for (int k0 = 0; k0 < 512; k0 += 64) {
        __syncthreads();
        #pragma unroll
        for (int p = 0; p < 4; p++) {
            int r = srow + p * 32;
            *(short8*)&As[r * PIT + scol] = *(const short8*)(Ab + (size_t)(bm + r) * 512 + k0 + scol);
            *(short8*)&Bs[r * PIT + scol] = *(const short8*)(Bt + (size_t)(bn + r) * 512 + k0 + scol);
        }
        __syncthreads();
        #pragma unroll
        for (int kk = 0; kk < 2; kk++) {
            short8 af[4], bf[4];
            #pragma unroll
            for (int i = 0; i < 4; i++)
                af[i] = *(const short8*)&As[(wr * 64 + i * 16 + nn) * PIT + kk * 32 + qd * 8];
            #pragma unroll
            for (int j = 0; j < 4; j++)
                bf[j] = *(const short8*)&Bs[(wc * 64 + j * 16 + nn) * PIT + kk * 32 + qd * 8];
            #pragma unroll
            for (int i = 0; i < 4; i++)
                #pragma unroll
                for (int j = 0; j < 4; j++)
                    acc[i][j] = __builtin_amdgcn_mfma_f32_16x16x32_bf16(af[i], bf[j], acc[i][j], 0, 0, 0);
        }
    }
    #pragma unroll
    for (int j = 0; j < 4; j++) {
        int col = bn + wc * 64 + j * 16 + nn;
        float bb = bias[col];
        #pragma unroll
        for (int i = 0; i < 4; i++) {
            int rbase = bm + wr * 64 + i * 16 + qd * 4;
            #pragma unroll
            for (int r = 0; r < 4; r++) {
                unsigned short hh = f2bf(silu_f(acc[i][j][r] + bb));
                if (col < 256) A2[(size_t)(rbase + r) * 1024 + col] = hh;
                else           qkvb[(size_t)(rbase + r) * 768 + col - 256] = hh;
            }
        }
    }
}

// ---------------- GEMM2 (MFMA bf16): out = x + A2 @ Wo ----------------
__global__ void __launch_bounds__(256) gemm2_mfma(
    const unsigned short* __restrict__ Ab, const unsigned short* __restrict__ Bt,
    const float* __restrict__ x, float* __restrict__ out)
{
    __shared__ unsigned short As[128 * PIT];
    __shared__ unsigned short Bs[128 * PIT];
    int tid = threadIdx.x;
    int lane = tid & 63, w = tid >> 6;
    int wr = w >> 1, wc = w & 1;
    int nn = lane & 15, qd = lane >> 4;
    int bm = blockIdx.y * 128, bn = blockIdx.x * 128;
    int srow = tid >> 3, scol = (tid & 7) * 8;

    f32x4 acc[4][4];
    #pragma unroll
    for (int i = 0; i < 4; i++)
        #pragma unroll
        for (int j = 0; j < 4; j++) acc[i][j] = (f32x4){0.f, 0.f, 0.f, 0.f};

    for (int k0 = 0; k0 < 1024; k0 += 64) {
        __syncthreads();
        #pragma unroll
        for (int p = 0; p < 4; p++) {
            int r = srow + p * 32;
            *(short8*)&As[r * PIT + scol] = *(const short8*)(Ab + (size_t)(bm + r) * 1024 + k0 + scol);
            *(short8*)&Bs[r * PIT + scol] = *(const short8*)(Bt + (size_t)(bn + r) * 1024 + k0 + scol);
        }
        __syncthreads();
        #pragma unroll
        for (int kk = 0; kk < 2; kk++) {
            short8 af[4], bf[4];
            #pragma unroll
            for (int i = 0; i < 4; i++)
                af[i] = *(const short8*)&As[(wr * 64 + i * 16 + nn) * PIT + kk * 32 + qd * 8];
            #pragma unroll
            for (int j = 0; j < 4; j++)
                bf[j] = *(const short8*)&Bs[(wc * 64 + j * 16 + nn) * PIT + kk * 32 + qd * 8];
            #pragma unroll
            for (int i = 0; i < 4; i++)
                #pragma unroll
                for (int j = 0; j < 4; j++)
                    acc[i][j] = __builtin_amdgcn_mfma_f32_16x16x32_bf16(af[i], bf[j], acc[i][j], 0, 0, 0);
        }
    }
    #pragma unroll
    for (int j = 0; j < 4; j++) {
        int col = bn + wc * 64 + j * 16 + nn;
        #pragma unroll
        for (int i = 0; i < 4; i++) {
            int rbase = bm + wr * 64 + i * 16 + qd * 4;
            #pragma unroll
            for (int r = 0; r < 4; r++) {
                size_t idx = (size_t)(rbase + r) * 512 + col;
                out[idx] = x[idx] + acc[i][j][r];
            }
        }
    }
}

// ---------------- Attention (MFMA bf16, wave-private m-split, no atomics) ----------------
// grid: (32 ntiles reversed, 16 bh), block 256 = 4 waves.
// Wave w processes m-chunks w, w+4, ... for ALL 64 n-cols of its block's n-tile.
// K A-frags come straight from global (prefetched 1 chunk ahead); V is staged
// transposed into a wave-PRIVATE LDS region (no __syncthreads in the loop).
// Epilogue: per-wave partials -> LDS (n-major), block reduce, plain float4 stores.
__global__ void __launch_bounds__(256, 2) attn_mfma_kernel(
    const unsigned short* __restrict__ qkvb,
    const int* __restrict__ offsets,
    const int* __restrict__ lengths,
    const int* __restrict__ num_targets,
    float* __restrict__ attn)
{
    int bh = blockIdx.y;
    int b = bh >> 2, h = bh & 3;
    int len = lengths[b];
    int n0 = (31 - (int)blockIdx.x) * 64;   // deep tiles dispatched first
    if (n0 >= len) return;
    int m_hi = min(n0 + 63, len - 1);
    int off = offsets[b];
    int max_id = len - num_targets[b];
    int tid = threadIdx.x, lane = tid & 63, w = tid >> 6;
    int nn = lane & 15, qd = lane >> 4;

    __shared__ __align__(16) char smem[69632];
    unsigned short* Vt = (unsigned short*)(smem + w * 9216);  // wave-private 64x72 bf16
    float* Os = (float*)smem;                                 // overlay: 4 x (64x68) f32

    // Q B-frags for all 4 n-groups, alpha=0.125 folded (exact pow2)
    short8 qf[4][2];
    #pragma unroll
    for (int g = 0; g < 4; g++) {
        int row = min(n0 + g * 16 + nn, len - 1);
        const unsigned short* base = qkvb + (size_t)(off + row) * 768 + 256 + h * 64;
        qf[g][0] = scale8_pow2(*(const short8*)(base + qd * 8), 0.125f);
        qf[g][1] = scale8_pow2(*(const short8*)(base + 32 + qd * 8), 0.125f);
    }

    f32x4 o_acc[4][4];   // [t: v-subtile][g: n-group], O^T C-layout
    #pragma unroll
    for (int t = 0; t < 4; t++)
        #pragma unroll
        for (int g = 0; g < 4; g++) o_acc[t][g] = (f32x4){0.f, 0.f, 0.f, 0.f};

    int fast_lim = min(n0, max_id);
    int r0 = (lane & 15) * 4, d0 = (lane >> 4) * 16;   // V staging: 4 rows x 16 dims per lane

    short8 kf[4][2], kn[4][2], vf[4][2], vn[4][2];
    int m_first = w * 64;
    if (m_first <= m_hi) {
        #pragma unroll
        for (int s = 0; s < 4; s++) {
            int row = min(m_first + s * 16 + nn, len - 1);
            const unsigned short* kb = qkvb + (size_t)(off + row) * 768 + 512 + h * 64 + qd * 8;
            kf[s][0] = *(const short8*)kb;
            kf[s][1] = *(const short8*)(kb + 32);
        }
        #pragma unroll
        for (int j = 0; j < 4; j++) {
            int row = min(m_first + r0 + j, len - 1);
            const unsigned short* vb = qkvb + (size_t)(off + row) * 768 + h * 64 + d0;
            vf[j][0] = *(const short8*)vb;
            vf[j][1] = *(const short8*)(vb + 8);
        }
    }

    for (int m0 = m_first; m0 <= m_hi; m0 += 256) {
        // publish prefetched V transposed: Vt[d][m] (wave-private -> no barrier)
        #pragma unroll
        for (int dd = 0; dd < 16; dd++) {
            int hh = dd >> 3, e = dd & 7;
            short4v pk;
            pk[0] = vf[0][hh][e]; pk[1] = vf[1][hh][e];
            pk[2] = vf[2][hh][e]; pk[3] = vf[3][hh][e];
            *(short4v*)&Vt[(d0 + dd) * PIT + r0] = pk;
        }
        // prefetch next chunk (K frags + V regs)
        int mnext = m0 + 256;
        if (mnext <= m_hi) {
            #pragma unroll
            for (int s = 0; s < 4; s++) {
                int row = min(mnext + s * 16 + nn, len - 1);
                const unsigned short* kb = qkvb + (size_t)(off + row) * 768 + 512 + h * 64 + qd * 8;
                kn[s][0] = *(const short8*)kb;
                kn[s][1] = *(const short8*)(kb + 32);
            }
            #pragma unroll
            for (int j = 0; j < 4; j++) {
                int row = min(mnext + r0 + j, len - 1);
                const unsigned short* vb = qkvb + (size_t)(off + row) * 768 + h * 64 + d0;
                vn[j][0] = *(const short8*)vb;
                vn[j][1] = *(const short8*)(vb + 8);
            }
        }
        bool fastp = (m0 + 63 < fast_lim);   // wave-uniform: chunk fully unmasked
        #pragma unroll
        for (int s = 0; s < 4; s++) {
            // S^T subtile: lane holds S^T[m=m0+s*16+qd*4+r][n=n0+g*16+nn]
            f32x4 st[4];
            #pragma unroll
            for (int g = 0; g < 4; g++) {
                st[g] = (f32x4){0.f, 0.f, 0.f, 0.f};
                st[g] = __builtin_amdgcn_mfma_f32_16x16x32_bf16(kf[s][0], qf[g][0], st[g], 0, 0, 0);
                st[g] = __builtin_amdgcn_mfma_f32_16x16x32_bf16(kf[s][1], qf[g][1], st[g], 0, 0, 0);
            }
            short4v bop[4];
            if (fastp) {
                #pragma unroll
                for (int g = 0; g < 4; g++)
                    #pragma unroll
                    for (int r = 0; r < 4; r++)
                        bop[g][r] = (short)f2bf_fast(silu_f(st[g][r]));
            } else {
                #pragma unroll
                for (int g = 0; g < 4; g++) {
                    int nc_ = n0 + g * 16 + nn;
                    int id_ = min(nc_, max_id);
                    #pragma unroll
                    for (int r = 0; r < 4; r++) {
                        int mcol = m0 + s * 16 + qd * 4 + r;
                        bool ok = (mcol < id_) || (mcol == nc_);
                        bop[g][r] = (short)f2bf_fast(ok ? silu_f(st[g][r]) : 0.f);
                    }
                }
            }
            // O^T += V^T x P^T
            #pragma unroll
            for (int t = 0; t < 4; t++) {
                short4v aop = *(const short4v*)&Vt[(t * 16 + nn) * PIT + s * 16 + qd * 4];
                #pragma unroll
                for (int g = 0; g < 4; g++)
                    o_acc[t][g] = __builtin_amdgcn_mfma_f32_16x16x16bf16_1k(aop, bop[g], o_acc[t][g], 0, 0, 0);
            }
        }
        if (mnext <= m_hi) {
            #pragma unroll
            for (int s = 0; s < 4; s++) { kf[s][0] = kn[s][0]; kf[s][1] = kn[s][1]; }
            #pragma unroll
            for (int j = 0; j < 4; j++) { vf[j][0] = vn[j][0]; vf[j][1] = vn[j][1]; }
        }
    }

    // ---- block reduce over waves, plain coalesced store ----
    __syncthreads();   // all waves done with their Vt regions
    const float invN = 1.f / (float)NSEQ;
    float* Ow = Os + w * 4352;   // 64 x 68
    #pragma unroll
    for (int t = 0; t < 4; t++)
        #pragma unroll
        for (int g = 0; g < 4; g++) {
            f32x4 v = o_acc[t][g] * invN;
            *(f32x4*)&Ow[(g * 16 + nn) * 68 + t * 16 + qd * 4] = v;  // O[n][v]
        }
    __syncthreads();
    int rr = tid >> 2, cs = (tid & 3) * 16;
    if (n0 + rr < len) {
        float* dst = attn + (size_t)(off + n0 + rr) * 256 + h * 64 + cs;
        #pragma unroll
        for (int q4 = 0; q4 < 4; q4++) {
            f32x4 v = (f32x4){0.f, 0.f, 0.f, 0.f};
            #pragma unroll
            for (int w2 = 0; w2 < 4; w2++)
                v += *(const f32x4*)&Os[w2 * 4352 + rr * 68 + cs + q4 * 4];
            *(f32x4*)(dst + q4 * 4) = v;
        }
    }
}

extern "C" void kernel_launch(void* const* d_in, const int* in_sizes, int n_in,
                              void* d_out, int out_size, void* d_ws, size_t ws_size,
                              hipStream_t stream)
{
    const float* x          = (const float*)d_in[0];
    const int*   x_lengths  = (const int*)d_in[1];
    const int*   x_offsets  = (const int*)d_in[2];
    // d_in[3] = max_seq_len (2048, hardcoded as NSEQ)
    const int*   num_targets = (const int*)d_in[4];
    const float* uvqk_w     = (const float*)d_in[5];
    const float* uvqk_b     = (const float*)d_in[6];
    const float* in_w       = (const float*)d_in[7];
    const float* in_b       = (const float*)d_in[8];
    const float* out_w      = (const float*)d_in[9];
    const float* out_b      = (const float*)d_in[10];
    const float* Wo         = (const float*)d_in[11];
    float* out = (float*)d_out;

    int L = in_sizes[0] / 512;   // 6400
    int B = in_sizes[1];         // 4

    char* ws = (char*)d_ws;
    size_t o = 0;
    float* attn = (float*)(ws + o);          o += (size_t)L * 256 * 4;   // fp32 attn
    unsigned short* nxb  = (unsigned short*)(ws + o); o += (size_t)L * 512 * 2;
    unsigned short* A2   = (unsigned short*)(ws + o); o += (size_t)L * 1024 * 2;
    unsigned short* qkvb = (unsigned short*)(ws + o); o += (size_t)L * 768 * 2;
    unsigned short* W1t  = (unsigned short*)(ws + o); o += (size_t)1024 * 512 * 2;
    unsigned short* W2t  = (unsigned short*)(ws + o); o += (size_t)512 * 1024 * 2;

    // 0) weight transpose + cast (per-launch; ~3 MB)
    transpose_to_bf16<<<dim3(1024 / 32, 512 / 32), 256, 0, stream>>>(uvqk_w, W1t, 512, 1024);
    transpose_to_bf16<<<dim3(512 / 32, 1024 / 32), 256, 0, stream>>>(Wo, W2t, 1024, 512);

    // 1) input LN -> bf16 nx; raw x -> bf16 A2[:,256:768)
    ln512_kernel<<<L, 256, 0, stream>>>(x, in_w, in_b, nxb, A2);

    // 2) uvqk = silu(nx @ W1 + b): u -> A2[:,0:256), v/q/k -> qkvb
    dim3 g1(1024 / 128, L / 128);
    gemm1_mfma<<<g1, 256, 0, stream>>>(nxb, W1t, uvqk_b, A2, qkvb);

    // 3) attention (wave-private m-split, no atomics, no memset needed)
    dim3 g2(NSEQ / 64, 16);
    attn_mfma_kernel<<<g2, 256, 0, stream>>>(qkvb, x_offsets, x_lengths, num_targets, attn);

    // 4) output LN -> bf16 A2[:,768:1024)
    ln256_kernel<<<L, 256, 0, stream>>>(attn, out_w, out_b, A2);

    // 5) out = x + A2 @ Wo
    dim3 g3(512 / 128, L / 128);
    gemm2_mfma<<<g3, 256, 0, stream>>>(A2, W2t, x, out);
}

// Round 8
// 178.913 us; speedup vs baseline: 1.3154x; 1.0554x over previous
//
#include <hip/hip_runtime.h>
#include <math.h>

// Problem constants (fixed by setup_inputs):
//   B=4, N=2048, D=512, H=4, A=64, V=64, L=6400
//   qkvb (bf16, L x 768): [0:256)=v, [256:512)=q, [512:768)=k
//   A2   (bf16, L x 1024): [0:256)=u, [256:768)=x, [768:1024)=y
#define NSEQ 2048
#define PIT 72    // attention LDS pitch (bf16 elems)
#define GP 40     // gemm LDS pitch for BK=32 (32 + 8 pad, odd multiple of 8)

typedef __attribute__((ext_vector_type(8))) short short8;   // 8 bf16 = 4 VGPR
typedef __attribute__((ext_vector_type(4))) short short4v;  // 4 bf16 = 2 VGPR
typedef __attribute__((ext_vector_type(4))) float f32x4;    // MFMA acc

// fast silu: z * rcp(1 + exp(-z)) — v_rcp_f32 (1 ulp) instead of the
// correctly-rounded div sequence (~12 VALU). bf16 outputs don't see the diff.
__device__ __forceinline__ float silu_f(float z) {
    return z * __builtin_amdgcn_rcpf(1.f + __expf(-z));
}

__device__ __forceinline__ unsigned short f2bf(float f) {
    unsigned int u = __float_as_uint(f);
    u += 0x7fffu + ((u >> 16) & 1u);   // RNE (finite inputs only)
    return (unsigned short)(u >> 16);
}

__device__ __forceinline__ unsigned short f2bf_fast(float f) {
    return (unsigned short)((__float_as_uint(f) + 0x8000u) >> 16);
}

// exact for power-of-2 scale
__device__ __forceinline__ short8 scale8_pow2(short8 v, float s) {
    short8 r;
    #pragma unroll
    for (int i = 0; i < 8; i++) {
        float f = __uint_as_float(((unsigned int)(unsigned short)v[i]) << 16) * s;
        r[i] = (short)(unsigned short)(__float_as_uint(f) >> 16);
    }
    return r;
}

// ---------------- transpose + cast: Wt[c][r] = bf16(W[r][c]) ----------------
__global__ void __launch_bounds__(256) transpose_to_bf16(
    const float* __restrict__ W, unsigned short* __restrict__ Wt, int R, int C)
{
    __shared__ float t[32][33];
    int tid = threadIdx.x;
    int tr = tid >> 5, tc = tid & 31;
    int r0 = blockIdx.y * 32, c0 = blockIdx.x * 32;
    #pragma unroll
    for (int p = 0; p < 4; p++)
        t[tr + p * 8][tc] = W[(size_t)(r0 + tr + p * 8) * C + c0 + tc];
    __syncthreads();
    #pragma unroll
    for (int p = 0; p < 4; p++)
        Wt[(size_t)(c0 + tr + p * 8) * R + r0 + tc] = f2bf(t[tc][tr + p * 8]);
}

// ---------------- LN over 512 (input) -> bf16 nx; also bf16 raw x into A2 ----------------
__global__ void __launch_bounds__(256) ln512_kernel(
    const float* __restrict__ x, const float* __restrict__ w,
    const float* __restrict__ b,
    unsigned short* __restrict__ nxb, unsigned short* __restrict__ A2)
{
    int row = blockIdx.x;
    int tid = threadIdx.x;
    const float* xr = x + (size_t)row * 512;
    float2 v = *(const float2*)(xr + tid * 2);
    float s = v.x + v.y;
    float sq = v.x * v.x + v.y * v.y;
    for (int o = 32; o > 0; o >>= 1) { s += __shfl_down(s, o); sq += __shfl_down(sq, o); }
    __shared__ float red[8];
    int wv = tid >> 6;
    if ((tid & 63) == 0) { red[wv] = s; red[4 + wv] = sq; }
    __syncthreads();
    float ts = red[0] + red[1] + red[2] + red[3];
    float tq = red[4] + red[5] + red[6] + red[7];
    float mu = ts * (1.f / 512.f);
    float var = tq * (1.f / 512.f) - mu * mu;
    float rs = rsqrtf(var + 1e-6f);
    float2 wv2 = *(const float2*)(w + tid * 2);
    float2 bv  = *(const float2*)(b + tid * 2);
    ushort2 hn, hx;
    hn.x = f2bf((v.x - mu) * rs * wv2.x + bv.x);
    hn.y = f2bf((v.y - mu) * rs * wv2.y + bv.y);
    hx.x = f2bf(v.x);
    hx.y = f2bf(v.y);
    *(ushort2*)(nxb + (size_t)row * 512 + tid * 2) = hn;
    *(ushort2*)(A2 + (size_t)row * 1024 + 256 + tid * 2) = hx;
}

// ---------------- LN over 256 (output) -> bf16 y into A2 ----------------
__global__ void __launch_bounds__(256) ln256_kernel(
    const float* __restrict__ a, const float* __restrict__ w,
    const float* __restrict__ b, unsigned short* __restrict__ A2)
{
    int row = blockIdx.x;
    int tid = threadIdx.x;
    float v = a[(size_t)row * 256 + tid];
    float s = v, sq = v * v;
    for (int o = 32; o > 0; o >>= 1) { s += __shfl_down(s, o); sq += __shfl_down(sq, o); }
    __shared__ float red[8];
    int wv = tid >> 6;
    if ((tid & 63) == 0) { red[wv] = s; red[4 + wv] = sq; }
    __syncthreads();
    float ts = red[0] + red[1] + red[2] + red[3];
    float tq = red[4] + red[5] + red[6] + red[7];
    float mu = ts * (1.f / 256.f);
    float var = tq * (1.f / 256.f) - mu * mu;
    float rs = rsqrtf(var + 1e-6f);
    A2[(size_t)row * 1024 + 768 + tid] = f2bf((v - mu) * rs * w[tid] + b[tid]);
}

// ---------------- GEMM1 (MFMA bf16, 128x64 tile, BK=32, LDS dbuf + reg prefetch) ----
// A: nxb (L x 512), B: W1t (1024 x 512 N-major). silu(A@B^T + bias) -> A2 u / qkvb.
__global__ void __launch_bounds__(256) gemm1_mfma(
    const unsigned short* __restrict__ Ab, const unsigned short* __restrict__ Bt,
    const float* __restrict__ bias,
    unsigned short* __restrict__ A2, unsigned short* __restrict__ qkvb)
{
    constexpr int K = 512, KIT = K / 32;
    __shared__ unsigned short As[2][128 * GP];
    __shared__ unsigned short Bs[2][64 * GP];
    int tid = threadIdx.x, lane = tid & 63, w = tid >> 6;
    int nn = lane & 15, qd = lane >> 4;
    int bm = blockIdx.y * 128, bn = blockIdx.x * 64;
    int arow = tid >> 1, aseg = (tid & 1) * 16;
    int brow = tid >> 2, bseg = (tid & 3) * 8;
    const unsigned short* Ag = Ab + (size_t)(bm + arow) * K + aseg;
    const unsigned short* Bg = Bt + (size_t)(bn + brow) * K + bseg;

    short8 pa0 = *(const short8*)Ag;
    short8 pa1 = *(const short8*)(Ag + 8);
    short8 pb0 = *(const short8*)Bg;

    f32x4 acc[2][4];
    #pragma unroll
    for (int i = 0; i < 2; i++)
        #pragma unroll
        for (int j = 0; j < 4; j++) acc[i][j] = (f32x4){0.f, 0.f, 0.f, 0.f};

    int buf = 0;
    for (int it = 0; it < KIT; ++it) {
        *(short8*)&As[buf][arow * GP + aseg]     = pa0;
        *(short8*)&As[buf][arow * GP + aseg + 8] = pa1;
        *(short8*)&Bs[buf][brow * GP + bseg]     = pb0;
        __syncthreads();
        if (it + 1 < KIT) {          // next tile's loads fly during this compute
            int k0 = (it + 1) * 32;
            pa0 = *(const short8*)(Ag + k0);
            pa1 = *(const short8*)(Ag + k0 + 8);
            pb0 = *(const short8*)(Bg + k0);
        }
        short8 af[2], bf[4];
        #pragma unroll
        for (int i = 0; i < 2; i++)
            af[i] = *(const short8*)&As[buf][(w * 32 + i * 16 + nn) * GP + qd * 8];
        #pragma unroll
        for (int j = 0; j < 4; j++)
            bf[j] = *(const short8*)&Bs[buf][(j * 16 + nn) * GP + qd * 8];
        #pragma unroll
        for (int i = 0; i < 2; i++)
            #pragma unroll
            for (int j = 0; j < 4; j++)
                acc[i][j] = __builtin_amdgcn_mfma_f32_16x16x32_bf16(af[i], bf[j], acc[i][j], 0, 0, 0);
        buf ^= 1;
    }
    bool isU = (bn < 256);   // block-uniform
    #pragma unroll
    for (int j = 0; j < 4; j++) {
        int col = bn + j * 16 + nn;
        float bb = bias[col];
        #pragma unroll
        for (int i = 0; i < 2; i++) {
            int rbase = bm + w * 32 + i * 16 + qd * 4;
            #pragma unroll
            for (int r = 0; r < 4; r++) {
                unsigned short hh = f2bf(silu_f(acc[i][j][r] + bb));
                if (isU) A2[(size_t)(rbase + r) * 1024 + col] = hh;
                else     qkvb[(size_t)(rbase + r) * 768 + col - 256] = hh;
            }
        }
    }
}

// ---------------- GEMM2 (MFMA bf16, same skeleton, K=1024): out = x + A2 @ Wo ----
__global__ void __launch_bounds__(256) gemm2_mfma(
    const unsigned short* __restrict__ Ab, const unsigned short* __restrict__ Bt,
    const float* __restrict__ x, float* __restrict__ out)
{
    constexpr int K = 1024, KIT = K / 32;
    __shared__ unsigned short As[2][128 * GP];
    __shared__ unsigned short Bs[2][64 * GP];
    int tid = threadIdx.x, lane = tid & 63, w = tid >> 6;
    int nn = lane & 15, qd = lane >> 4;
    int bm = blockIdx.y * 128, bn = blockIdx.x * 64;
    int arow = tid >> 1, aseg = (tid & 1) * 16;
    int brow = tid >> 2, bseg = (tid & 3) * 8;
    const unsigned short* Ag = Ab + (size_t)(bm + arow) * K + aseg;
    const unsigned short* Bg = Bt + (size_t)(bn + brow) * K + bseg;

    short8 pa0 = *(const short8*)Ag;
    short8 pa1 = *(const short8*)(Ag + 8);
    short8 pb0 = *(const short8*)Bg;

    f32x4 acc[2][4];
    #pragma unroll
    for (int i = 0; i < 2; i++)
        #pragma unroll
        for (int j = 0; j < 4; j++) acc[i][j] = (f32x4){0.f, 0.f, 0.f, 0.f};

    int buf = 0;
    for (int it = 0; it < KIT; ++it) {
        *(short8*)&As[buf][arow * GP + aseg]     = pa0;
        *(short8*)&As[buf][arow * GP + aseg + 8] = pa1;
        *(short8*)&Bs[buf][brow * GP + bseg]     = pb0;
        __syncthreads();
        if (it + 1 < KIT) {
            int k0 = (it + 1) * 32;
            pa0 = *(const short8*)(Ag + k0);
            pa1 = *(const short8*)(Ag + k0 + 8);
            pb0 = *(const short8*)(Bg + k0);
        }
        short8 af[2], bf[4];
        #pragma unroll
        for (int i = 0; i < 2; i++)
            af[i] = *(const short8*)&As[buf][(w * 32 + i * 16 + nn) * GP + qd * 8];
        #pragma unroll
        for (int j = 0; j < 4; j++)
            bf[j] = *(const short8*)&Bs[buf][(j * 16 + nn) * GP + qd * 8];
        #pragma unroll
        for (int i = 0; i < 2; i++)
            #pragma unroll
            for (int j = 0; j < 4; j++)
                acc[i][j] = __builtin_amdgcn_mfma_f32_16x16x32_bf16(af[i], bf[j], acc[i][j], 0, 0, 0);
        buf ^= 1;
    }
    #pragma unroll
    for (int j = 0; j < 4; j++) {
        int col = bn + j * 16 + nn;
        #pragma unroll
        for (int i = 0; i < 2; i++) {
            int rbase = bm + w * 32 + i * 16 + qd * 4;
            #pragma unroll
            for (int r = 0; r < 4; r++) {
                size_t idx = (size_t)(rbase + r) * 512 + col;
                out[idx] = x[idx] + acc[i][j][r];
            }
        }
    }
}

// ---------------- Attention (MFMA bf16, wave-private m-split, no atomics) ----------------
__global__ void __launch_bounds__(256, 2) attn_mfma_kernel(
    const unsigned short* __restrict__ qkvb,
    const int* __restrict__ offsets,
    const int* __restrict__ lengths,
    const int* __restrict__ num_targets,
    float* __restrict__ attn)
{
    int bh = blockIdx.y;
    int b = bh >> 2, h = bh & 3;
    int len = lengths[b];
    int n0 = (31 - (int)blockIdx.x) * 64;   // deep tiles dispatched first
    if (n0 >= len) return;
    int m_hi = min(n0 + 63, len - 1);
    int off = offsets[b];
    int max_id = len - num_targets[b];
    int tid = threadIdx.x, lane = tid & 63, w = tid >> 6;
    int nn = lane & 15, qd = lane >> 4;

    __shared__ __align__(16) char smem[69632];
    unsigned short* Vt = (unsigned short*)(smem + w * 9216);  // wave-private 64x72 bf16
    float* Os = (float*)smem;                                 // overlay: 4 x (64x68) f32

    // Q B-frags for all 4 n-groups, alpha=0.125 folded (exact pow2)
    short8 qf[4][2];
    #pragma unroll
    for (int g = 0; g < 4; g++) {
        int row = min(n0 + g * 16 + nn, len - 1);
        const unsigned short* base = qkvb + (size_t)(off + row) * 768 + 256 + h * 64;
        qf[g][0] = scale8_pow2(*(const short8*)(base + qd * 8), 0.125f);
        qf[g][1] = scale8_pow2(*(const short8*)(base + 32 + qd * 8), 0.125f);
    }

    f32x4 o_acc[4][4];   // [t: v-subtile][g: n-group], O^T C-layout
    #pragma unroll
    for (int t = 0; t < 4; t++)
        #pragma unroll
        for (int g = 0; g < 4; g++) o_acc[t][g] = (f32x4){0.f, 0.f, 0.f, 0.f};

    int fast_lim = min(n0, max_id);
    int r0 = (lane & 15) * 4, d0 = (lane >> 4) * 16;   // V staging: 4 rows x 16 dims

    short8 kf[4][2], kn[4][2], vf[4][2];
    int m_first = w * 64;
    if (m_first <= m_hi) {
        #pragma unroll
        for (int s = 0; s < 4; s++) {
            int row = min(m_first + s * 16 + nn, len - 1);
            const unsigned short* kb = qkvb + (size_t)(off + row) * 768 + 512 + h * 64 + qd * 8;
            kf[s][0] = *(const short8*)kb;
            kf[s][1] = *(const short8*)(kb + 32);
        }
        #pragma unroll
        for (int j = 0; j < 4; j++) {
            int row = min(m_first + r0 + j, len - 1);
            const unsigned short* vb = qkvb + (size_t)(off + row) * 768 + h * 64 + d0;
            vf[j][0] = *(const short8*)vb;
            vf[j][1] = *(const short8*)(vb + 8);
        }
    }

    for (int m0 = m_first; m0 <= m_hi; m0 += 256) {
        // publish V transposed into wave-private LDS (no barrier needed)
        #pragma unroll
        for (int dd = 0; dd < 16; dd++) {
            int hh = dd >> 3, e = dd & 7;
            short4v pk;
            pk[0] = vf[0][hh][e]; pk[1] = vf[1][hh][e];
            pk[2] = vf[2][hh][e]; pk[3] = vf[3][hh][e];
            *(short4v*)&Vt[(d0 + dd) * PIT + r0] = pk;
        }
        int mnext = m0 + 256;
        if (mnext <= m_hi) {
            // reload vf with next chunk (WAR on the just-issued ds_writes is
            // handled by issue order; loads land during the s-loop below)
            #pragma unroll
            for (int j = 0; j < 4; j++) {
                int row = min(mnext + r0 + j, len - 1);
                const unsigned short* vb = qkvb + (size_t)(off + row) * 768 + h * 64 + d0;
                vf[j][0] = *(const short8*)vb;
                vf[j][1] = *(const short8*)(vb + 8);
            }
            #pragma unroll
            for (int s = 0; s < 4; s++) {
                int row = min(mnext + s * 16 + nn, len - 1);
                const unsigned short* kb = qkvb + (size_t)(off + row) * 768 + 512 + h * 64 + qd * 8;
                kn[s][0] = *(const short8*)kb;
                kn[s][1] = *(const short8*)(kb + 32);
            }
        }
        bool fastp = (m0 + 63 < fast_lim);   // wave-uniform: chunk fully unmasked
        #pragma unroll
        for (int s = 0; s < 4; s++) {
            f32x4 st[4];
            #pragma unroll
            for (int g = 0; g < 4; g++) {
                st[g] = (f32x4){0.f, 0.f, 0.f, 0.f};
                st[g] = __builtin_amdgcn_mfma_f32_16x16x32_bf16(kf[s][0], qf[g][0], st[g], 0, 0, 0);
                st[g] = __builtin_amdgcn_mfma_f32_16x16x32_bf16(kf[s][1], qf[g][1], st[g], 0, 0, 0);
            }
            short4v bop[4];
            if (fastp) {
                #pragma unroll
                for (int g = 0; g < 4; g++)
                    #pragma unroll
                    for (int r = 0; r < 4; r++)
                        bop[g][r] = (short)f2bf_fast(silu_f(st[g][r]));
            } else {
                #pragma unroll
                for (int g = 0; g < 4; g++) {
                    int nc_ = n0 + g * 16 + nn;
                    int id_ = min(nc_, max_id);
                    #pragma unroll
                    for (int r = 0; r < 4; r++) {
                        int mcol = m0 + s * 16 + qd * 4 + r;
                        bool ok = (mcol < id_) || (mcol == nc_);
                        bop[g][r] = (short)f2bf_fast(ok ? silu_f(st[g][r]) : 0.f);
                    }
                }
            }
            #pragma unroll
            for (int t = 0; t < 4; t++) {
                short4v aop = *(const short4v*)&Vt[(t * 16 + nn) * PIT + s * 16 + qd * 4];
                #pragma unroll
                for (int g = 0; g < 4; g++)
                    o_acc[t][g] = __builtin_amdgcn_mfma_f32_16x16x16bf16_1k(aop, bop[g], o_acc[t][g], 0, 0, 0);
            }
        }
        if (mnext <= m_hi) {
            #pragma unroll
            for (int s = 0; s < 4; s++) { kf[s][0] = kn[s][0]; kf[s][1] = kn[s][1]; }
        }
    }

    // ---- block reduce over waves, plain coalesced store ----
    __syncthreads();   // all waves done with their Vt regions
    const float invN = 1.f / (float)NSEQ;
    float* Ow = Os + w * 4352;   // 64 x 68
    #pragma unroll
    for (int t = 0; t < 4; t++)
        #pragma unroll
        for (int g = 0; g < 4; g++) {
            f32x4 v = o_acc[t][g] * invN;
            *(f32x4*)&Ow[(g * 16 + nn) * 68 + t * 16 + qd * 4] = v;  // O[n][v]
        }
    __syncthreads();
    int rr = tid >> 2, cs = (tid & 3) * 16;
    if (n0 + rr < len) {
        float* dst = attn + (size_t)(off + n0 + rr) * 256 + h * 64 + cs;
        #pragma unroll
        for (int q4 = 0; q4 < 4; q4++) {
            f32x4 v = (f32x4){0.f, 0.f, 0.f, 0.f};
            #pragma unroll
            for (int w2 = 0; w2 < 4; w2++)
                v += *(const f32x4*)&Os[w2 * 4352 + rr * 68 + cs + q4 * 4];
            *(f32x4*)(dst + q4 * 4) = v;
        }
    }
}

extern "C" void kernel_launch(void* const* d_in, const int* in_sizes, int n_in,
                              void* d_out, int out_size, void* d_ws, size_t ws_size,
                              hipStream_t stream)
{
    const float* x          = (const float*)d_in[0];
    const int*   x_lengths  = (const int*)d_in[1];
    const int*   x_offsets  = (const int*)d_in[2];
    // d_in[3] = max_seq_len (2048, hardcoded as NSEQ)
    const int*   num_targets = (const int*)d_in[4];
    const float* uvqk_w     = (const float*)d_in[5];
    const float* uvqk_b     = (const float*)d_in[6];
    const float* in_w       = (const float*)d_in[7];
    const float* in_b       = (const float*)d_in[8];
    const float* out_w      = (const float*)d_in[9];
    const float* out_b      = (const float*)d_in[10];
    const float* Wo         = (const float*)d_in[11];
    float* out = (float*)d_out;

    int L = in_sizes[0] / 512;   // 6400
    int B = in_sizes[1];         // 4

    char* ws = (char*)d_ws;
    size_t o = 0;
    float* attn = (float*)(ws + o);          o += (size_t)L * 256 * 4;   // fp32 attn
    unsigned short* nxb  = (unsigned short*)(ws + o); o += (size_t)L * 512 * 2;
    unsigned short* A2   = (unsigned short*)(ws + o); o += (size_t)L * 1024 * 2;
    unsigned short* qkvb = (unsigned short*)(ws + o); o += (size_t)L * 768 * 2;
    unsigned short* W1t  = (unsigned short*)(ws + o); o += (size_t)1024 * 512 * 2;
    unsigned short* W2t  = (unsigned short*)(ws + o); o += (size_t)512 * 1024 * 2;

    // 0) weight transpose + cast (per-launch; ~3 MB)
    transpose_to_bf16<<<dim3(1024 / 32, 512 / 32), 256, 0, stream>>>(uvqk_w, W1t, 512, 1024);
    transpose_to_bf16<<<dim3(512 / 32, 1024 / 32), 256, 0, stream>>>(Wo, W2t, 1024, 512);

    // 1) input LN -> bf16 nx; raw x -> bf16 A2[:,256:768)
    ln512_kernel<<<L, 256, 0, stream>>>(x, in_w, in_b, nxb, A2);

    // 2) uvqk = silu(nx @ W1 + b): u -> A2[:,0:256), v/q/k -> qkvb
    dim3 g1(1024 / 64, L / 128);
    gemm1_mfma<<<g1, 256, 0, stream>>>(nxb, W1t, uvqk_b, A2, qkvb);

    // 3) attention (wave-private m-split, no atomics)
    dim3 g2(NSEQ / 64, 16);
    attn_mfma_kernel<<<g2, 256, 0, stream>>>(qkvb, x_offsets, x_lengths, num_targets, attn);

    // 4) output LN -> bf16 A2[:,768:1024)
    ln256_kernel<<<L, 256, 0, stream>>>(attn, out_w, out_b, A2);

    // 5) out = x + A2 @ Wo
    dim3 g3(512 / 64, L / 128);
    gemm2_mfma<<<g3, 256, 0, stream>>>(A2, W2t, x, out);
}

// Round 9
// 170.675 us; speedup vs baseline: 1.3789x; 1.0483x over previous
//
#include <hip/hip_runtime.h>
#include <math.h>

// Problem constants (fixed by setup_inputs):
//   B=4, N=2048, D=512, H=4, A=64, V=64, L=6400
//   qkvb (bf16, L x 768): [0:256)=v, [256:512)=q, [512:768)=k
//   A2   (bf16, L x 1024): [0:256)=u, [256:768)=x, [768:1024)=y
#define NSEQ 2048
#define PIT 72    // LDS pitch (bf16 elems): 144B rows -> 4-bank row shift, b128 reads 2-way (free)

typedef __attribute__((ext_vector_type(8))) short short8;   // 8 bf16 = 4 VGPR
typedef __attribute__((ext_vector_type(4))) short short4v;  // 4 bf16 = 2 VGPR
typedef __attribute__((ext_vector_type(4))) float f32x4;    // MFMA acc

// fast silu: z * rcp(1 + exp(-z)) — 1-ulp rcp instead of correctly-rounded divide
__device__ __forceinline__ float silu_f(float z) {
    return z * __builtin_amdgcn_rcpf(1.f + __expf(-z));
}

__device__ __forceinline__ unsigned short f2bf(float f) {
    unsigned int u = __float_as_uint(f);
    u += 0x7fffu + ((u >> 16) & 1u);   // RNE (finite inputs only)
    return (unsigned short)(u >> 16);
}

__device__ __forceinline__ unsigned short f2bf_fast(float f) {
    return (unsigned short)((__float_as_uint(f) + 0x8000u) >> 16);
}

// exact for power-of-2 scale
__device__ __forceinline__ short8 scale8_pow2(short8 v, float s) {
    short8 r;
    #pragma unroll
    for (int i = 0; i < 8; i++) {
        float f = __uint_as_float(((unsigned int)(unsigned short)v[i]) << 16) * s;
        r[i] = (short)(unsigned short)(__float_as_uint(f) >> 16);
    }
    return r;
}

// ---------------- transpose + cast: Wt[c][r] = bf16(W[r][c]) ----------------
__global__ void __launch_bounds__(256) transpose_to_bf16(
    const float* __restrict__ W, unsigned short* __restrict__ Wt, int R, int C)
{
    __shared__ float t[32][33];
    int tid = threadIdx.x;
    int tr = tid >> 5, tc = tid & 31;
    int r0 = blockIdx.y * 32, c0 = blockIdx.x * 32;
    #pragma unroll
    for (int p = 0; p < 4; p++)
        t[tr + p * 8][tc] = W[(size_t)(r0 + tr + p * 8) * C + c0 + tc];
    __syncthreads();
    #pragma unroll
    for (int p = 0; p < 4; p++)
        Wt[(size_t)(c0 + tr + p * 8) * R + r0 + tc] = f2bf(t[tc][tr + p * 8]);
}

// ---------------- LN over 512 (input), 2 rows/block -> bf16 nx; raw x -> A2 ----------------
__global__ void __launch_bounds__(256) ln512_kernel(
    const float* __restrict__ x, const float* __restrict__ w,
    const float* __restrict__ b,
    unsigned short* __restrict__ nxb, unsigned short* __restrict__ A2)
{
    int tid = threadIdx.x;
    int r = tid >> 7;                       // 0,1: which row of the pair
    int row = blockIdx.x * 2 + r;
    int c = (tid & 127) * 4;
    float4 v = *(const float4*)(x + (size_t)row * 512 + c);
    float s = v.x + v.y + v.z + v.w;
    float sq = v.x * v.x + v.y * v.y + v.z * v.z + v.w * v.w;
    for (int o = 32; o > 0; o >>= 1) { s += __shfl_down(s, o); sq += __shfl_down(sq, o); }
    __shared__ float red[8];
    int wv = tid >> 6;                      // waves 0,1 -> row 0; 2,3 -> row 1
    if ((tid & 63) == 0) { red[wv] = s; red[4 + wv] = sq; }
    __syncthreads();
    float ts = red[2 * r] + red[2 * r + 1];
    float tq = red[4 + 2 * r] + red[4 + 2 * r + 1];
    float mu = ts * (1.f / 512.f);
    float var = tq * (1.f / 512.f) - mu * mu;
    float rs = rsqrtf(var + 1e-6f);
    float4 wv4 = *(const float4*)(w + c);
    float4 bv4 = *(const float4*)(b + c);
    ushort4 hn, hx;
    hn.x = f2bf((v.x - mu) * rs * wv4.x + bv4.x);
    hn.y = f2bf((v.y - mu) * rs * wv4.y + bv4.y);
    hn.z = f2bf((v.z - mu) * rs * wv4.z + bv4.z);
    hn.w = f2bf((v.w - mu) * rs * wv4.w + bv4.w);
    hx.x = f2bf(v.x); hx.y = f2bf(v.y); hx.z = f2bf(v.z); hx.w = f2bf(v.w);
    *(ushort4*)(nxb + (size_t)row * 512 + c) = hn;
    *(ushort4*)(A2 + (size_t)row * 1024 + 256 + c) = hx;
}

// ---------------- LN over 256 (output), 2 rows/block -> bf16 y into A2 ----------------
__global__ void __launch_bounds__(256) ln256_kernel(
    const float* __restrict__ a, const float* __restrict__ w,
    const float* __restrict__ b, unsigned short* __restrict__ A2)
{
    int tid = threadIdx.x;
    int r = tid >> 7;
    int row = blockIdx.x * 2 + r;
    int c = (tid & 127) * 2;
    float2 v = *(const float2*)(a + (size_t)row * 256 + c);
    float s = v.x + v.y, sq = v.x * v.x + v.y * v.y;
    for (int o = 32; o > 0; o >>= 1) { s += __shfl_down(s, o); sq += __shfl_down(sq, o); }
    __shared__ float red[8];
    int wv = tid >> 6;
    if ((tid & 63) == 0) { red[wv] = s; red[4 + wv] = sq; }
    __syncthreads();
    float ts = red[2 * r] + red[2 * r + 1];
    float tq = red[4 + 2 * r] + red[4 + 2 * r + 1];
    float mu = ts * (1.f / 256.f);
    float var = tq * (1.f / 256.f) - mu * mu;
    float rs = rsqrtf(var + 1e-6f);
    float2 w2 = *(const float2*)(w + c);
    float2 b2 = *(const float2*)(b + c);
    ushort2 h;
    h.x = f2bf((v.x - mu) * rs * w2.x + b2.x);
    h.y = f2bf((v.y - mu) * rs * w2.y + b2.y);
    *(ushort2*)(A2 + (size_t)row * 1024 + 768 + c) = h;
}

// ---------------- GEMM1 (MFMA bf16, 64x128 tile, BK=64, reg prefetch) ----------------
// A: nxb (L x 512), B: W1t (1024 x 512, N-major). silu(A@B^T + bias) -> A2 u / qkvb.
// 800 blocks (3/CU); 16 MFMA per barrier-pair; next K-tile loads fly during compute.
__global__ void __launch_bounds__(256) gemm1_mfma(
    const unsigned short* __restrict__ Ab, const unsigned short* __restrict__ Bt,
    const float* __restrict__ bias,
    unsigned short* __restrict__ A2, unsigned short* __restrict__ qkvb)
{
    constexpr int K = 512, KIT = K / 64;
    __shared__ unsigned short As[64 * PIT];
    __shared__ unsigned short Bs[128 * PIT];
    int tid = threadIdx.x, lane = tid & 63, w = tid >> 6;
    int wr = w >> 1, wc = w & 1;
    int nn = lane & 15, qd = lane >> 4;
    int bm = blockIdx.y * 64, bn = blockIdx.x * 128;
    int arow = tid >> 2, ac0 = (tid & 3) * 16;      // A: 64 rows x 64 cols, 32B/thread
    int brow = tid >> 1, bc0 = (tid & 1) * 32;      // B: 128 rows x 64 cols, 64B/thread
    const unsigned short* Ag = Ab + (size_t)(bm + arow) * K + ac0;
    const unsigned short* Bg = Bt + (size_t)(bn + brow) * K + bc0;

    short8 pa0 = *(const short8*)Ag, pa1 = *(const short8*)(Ag + 8);
    short8 pb0 = *(const short8*)Bg, pb1 = *(const short8*)(Bg + 8);
    short8 pb2 = *(const short8*)(Bg + 16), pb3 = *(const short8*)(Bg + 24);

    f32x4 acc[2][4];
    #pragma unroll
    for (int i = 0; i < 2; i++)
        #pragma unroll
        for (int j = 0; j < 4; j++) acc[i][j] = (f32x4){0.f, 0.f, 0.f, 0.f};

    for (int it = 0; it < KIT; ++it) {
        __syncthreads();
        *(short8*)&As[arow * PIT + ac0]     = pa0;
        *(short8*)&As[arow * PIT + ac0 + 8] = pa1;
        *(short8*)&Bs[brow * PIT + bc0]      = pb0;
        *(short8*)&Bs[brow * PIT + bc0 + 8]  = pb1;
        *(short8*)&Bs[brow * PIT + bc0 + 16] = pb2;
        *(short8*)&Bs[brow * PIT + bc0 + 24] = pb3;
        __syncthreads();
        if (it + 1 < KIT) {
            int k0 = (it + 1) * 64;
            pa0 = *(const short8*)(Ag + k0); pa1 = *(const short8*)(Ag + k0 + 8);
            pb0 = *(const short8*)(Bg + k0); pb1 = *(const short8*)(Bg + k0 + 8);
            pb2 = *(const short8*)(Bg + k0 + 16); pb3 = *(const short8*)(Bg + k0 + 24);
        }
        #pragma unroll
        for (int kk = 0; kk < 2; kk++) {
            short8 af[2], bf[4];
            #pragma unroll
            for (int i = 0; i < 2; i++)
                af[i] = *(const short8*)&As[(wr * 32 + i * 16 + nn) * PIT + kk * 32 + qd * 8];
            #pragma unroll
            for (int j = 0; j < 4; j++)
                bf[j] = *(const short8*)&Bs[(wc * 64 + j * 16 + nn) * PIT + kk * 32 + qd * 8];
            #pragma unroll
            for (int i = 0; i < 2; i++)
                #pragma unroll
                for (int j = 0; j < 4; j++)
                    acc[i][j] = __builtin_amdgcn_mfma_f32_16x16x32_bf16(af[i], bf[j], acc[i][j], 0, 0, 0);
        }
    }
    bool isU = (bn < 256);   // block-uniform: 128-col tiles align with the u/vqk boundary
    #pragma unroll
    for (int j = 0; j < 4; j++) {
        int col = bn + wc * 64 + j * 16 + nn;
        float bb = bias[col];
        #pragma unroll
        for (int i = 0; i < 2; i++) {
            int rbase = bm + wr * 32 + i * 16 + qd * 4;
            #pragma unroll
            for (int r = 0; r < 4; r++) {
                unsigned short hh = f2bf(silu_f(acc[i][j][r] + bb));
                if (isU) A2[(size_t)(rbase + r) * 1024 + col] = hh;
                else     qkvb[(size_t)(rbase + r) * 768 + col - 256] = hh;
            }
        }
    }
}

// ---------------- GEMM2 (MFMA bf16, 64x128 tile, BK=64): out = x + A2 @ Wo ----------------
__global__ void __launch_bounds__(256) gemm2_mfma(
    const unsigned short* __restrict__ Ab, const unsigned short* __restrict__ Bt,
    const float* __restrict__ x, float* __restrict__ out)
{
    constexpr int K = 1024, KIT = K / 64;
    __shared__ unsigned short As[64 * PIT];
    __shared__ unsigned short Bs[128 * PIT];
    int tid = threadIdx.x, lane = tid & 63, w = tid >> 6;
    int wr = w >> 1, wc = w & 1;
    int nn = lane & 15, qd = lane >> 4;
    int bm = blockIdx.y * 64, bn = blockIdx.x * 128;
    int arow = tid >> 2, ac0 = (tid & 3) * 16;
    int brow = tid >> 1, bc0 = (tid & 1) * 32;
    const unsigned short* Ag = Ab + (size_t)(bm + arow) * K + ac0;
    const unsigned short* Bg = Bt + (size_t)(bn + brow) * K + bc0;

    short8 pa0 = *(const short8*)Ag, pa1 = *(const short8*)(Ag + 8);
    short8 pb0 = *(const short8*)Bg, pb1 = *(const short8*)(Bg + 8);
    short8 pb2 = *(const short8*)(Bg + 16), pb3 = *(const short8*)(Bg + 24);

    f32x4 acc[2][4];
    #pragma unroll
    for (int i = 0; i < 2; i++)
        #pragma unroll
        for (int j = 0; j < 4; j++) acc[i][j] = (f32x4){0.f, 0.f, 0.f, 0.f};

    for (int it = 0; it < KIT; ++it) {
        __syncthreads();
        *(short8*)&As[arow * PIT + ac0]     = pa0;
        *(short8*)&As[arow * PIT + ac0 + 8] = pa1;
        *(short8*)&Bs[brow * PIT + bc0]      = pb0;
        *(short8*)&Bs[brow * PIT + bc0 + 8]  = pb1;
        *(short8*)&Bs[brow * PIT + bc0 + 16] = pb2;
        *(short8*)&Bs[brow * PIT + bc0 + 24] = pb3;
        __syncthreads();
        if (it + 1 < KIT) {
            int k0 = (it + 1) * 64;
            pa0 = *(const short8*)(Ag + k0); pa1 = *(const short8*)(Ag + k0 + 8);
            pb0 = *(const short8*)(Bg + k0); pb1 = *(const short8*)(Bg + k0 + 8);
            pb2 = *(const short8*)(Bg + k0 + 16); pb3 = *(const short8*)(Bg + k0 + 24);
        }
        #pragma unroll
        for (int kk = 0; kk < 2; kk++) {
            short8 af[2], bf[4];
            #pragma unroll
            for (int i = 0; i < 2; i++)
                af[i] = *(const short8*)&As[(wr * 32 + i * 16 + nn) * PIT + kk * 32 + qd * 8];
            #pragma unroll
            for (int j = 0; j < 4; j++)
                bf[j] = *(const short8*)&Bs[(wc * 64 + j * 16 + nn) * PIT + kk * 32 + qd * 8];
            #pragma unroll
            for (int i = 0; i < 2; i++)
                #pragma unroll
                for (int j = 0; j < 4; j++)
                    acc[i][j] = __builtin_amdgcn_mfma_f32_16x16x32_bf16(af[i], bf[j], acc[i][j], 0, 0, 0);
        }
    }
    #pragma unroll
    for (int j = 0; j < 4; j++) {
        int col = bn + wc * 64 + j * 16 + nn;
        #pragma unroll
        for (int i = 0; i < 2; i++) {
            int rbase = bm + wr * 32 + i * 16 + qd * 4;
            #pragma unroll
            for (int r = 0; r < 4; r++) {
                size_t idx = (size_t)(rbase + r) * 512 + col;
                out[idx] = x[idx] + acc[i][j][r];
            }
        }
    }
}

// ---------------- Attention (MFMA bf16, wave-private m-split, no atomics) ----------------
__global__ void __launch_bounds__(256, 2) attn_mfma_kernel(
    const unsigned short* __restrict__ qkvb,
    const int* __restrict__ offsets,
    const int* __restrict__ lengths,
    const int* __restrict__ num_targets,
    float* __restrict__ attn)
{
    int bh = blockIdx.y;
    int b = bh >> 2, h = bh & 3;
    int len = lengths[b];
    int n0 = (31 - (int)blockIdx.x) * 64;   // deep tiles dispatched first
    if (n0 >= len) return;
    int m_hi = min(n0 + 63, len - 1);
    int off = offsets[b];
    int max_id = len - num_targets[b];
    int tid = threadIdx.x, lane = tid & 63, w = tid >> 6;
    int nn = lane & 15, qd = lane >> 4;

    __shared__ __align__(16) char smem[69632];
    unsigned short* Vt = (unsigned short*)(smem + w * 9216);  // wave-private 64x72 bf16
    float* Os = (float*)smem;                                 // overlay: 4 x (64x68) f32

    // Q B-frags for all 4 n-groups, alpha=0.125 folded (exact pow2)
    short8 qf[4][2];
    #pragma unroll
    for (int g = 0; g < 4; g++) {
        int row = min(n0 + g * 16 + nn, len - 1);
        const unsigned short* base = qkvb + (size_t)(off + row) * 768 + 256 + h * 64;
        qf[g][0] = scale8_pow2(*(const short8*)(base + qd * 8), 0.125f);
        qf[g][1] = scale8_pow2(*(const short8*)(base + 32 + qd * 8), 0.125f);
    }

    f32x4 o_acc[4][4];   // [t: v-subtile][g: n-group], O^T C-layout
    #pragma unroll
    for (int t = 0; t < 4; t++)
        #pragma unroll
        for (int g = 0; g < 4; g++) o_acc[t][g] = (f32x4){0.f, 0.f, 0.f, 0.f};

    int fast_lim = min(n0, max_id);
    int r0 = (lane & 15) * 4, d0 = (lane >> 4) * 16;   // V staging: 4 rows x 16 dims

    short8 kf[4][2], kn[4][2], vf[4][2];
    int m_first = w * 64;
    if (m_first <= m_hi) {
        #pragma unroll
        for (int s = 0; s < 4; s++) {
            int row = min(m_first + s * 16 + nn, len - 1);
            const unsigned short* kb = qkvb + (size_t)(off + row) * 768 + 512 + h * 64 + qd * 8;
            kf[s][0] = *(const short8*)kb;
            kf[s][1] = *(const short8*)(kb + 32);
        }
        #pragma unroll
        for (int j = 0; j < 4; j++) {
            int row = min(m_first + r0 + j, len - 1);
            const unsigned short* vb = qkvb + (size_t)(off + row) * 768 + h * 64 + d0;
            vf[j][0] = *(const short8*)vb;
            vf[j][1] = *(const short8*)(vb + 8);
        }
    }

    for (int m0 = m_first; m0 <= m_hi; m0 += 256) {
        #pragma unroll
        for (int dd = 0; dd < 16; dd++) {
            int hh = dd >> 3, e = dd & 7;
            short4v pk;
            pk[0] = vf[0][hh][e]; pk[1] = vf[1][hh][e];
            pk[2] = vf[2][hh][e]; pk[3] = vf[3][hh][e];
            *(short4v*)&Vt[(d0 + dd) * PIT + r0] = pk;
        }
        int mnext = m0 + 256;
        if (mnext <= m_hi) {
            #pragma unroll
            for (int j = 0; j < 4; j++) {
                int row = min(mnext + r0 + j, len - 1);
                const unsigned short* vb = qkvb + (size_t)(off + row) * 768 + h * 64 + d0;
                vf[j][0] = *(const short8*)vb;
                vf[j][1] = *(const short8*)(vb + 8);
            }
            #pragma unroll
            for (int s = 0; s < 4; s++) {
                int row = min(mnext + s * 16 + nn, len - 1);
                const unsigned short* kb = qkvb + (size_t)(off + row) * 768 + 512 + h * 64 + qd * 8;
                kn[s][0] = *(const short8*)kb;
                kn[s][1] = *(const short8*)(kb + 32);
            }
        }
        bool fastp = (m0 + 63 < fast_lim);
        #pragma unroll
        for (int s = 0; s < 4; s++) {
            f32x4 st[4];
            #pragma unroll
            for (int g = 0; g < 4; g++) {
                st[g] = (f32x4){0.f, 0.f, 0.f, 0.f};
                st[g] = __builtin_amdgcn_mfma_f32_16x16x32_bf16(kf[s][0], qf[g][0], st[g], 0, 0, 0);
                st[g] = __builtin_amdgcn_mfma_f32_16x16x32_bf16(kf[s][1], qf[g][1], st[g], 0, 0, 0);
            }
            short4v bop[4];
            if (fastp) {
                #pragma unroll
                for (int g = 0; g < 4; g++)
                    #pragma unroll
                    for (int r = 0; r < 4; r++)
                        bop[g][r] = (short)f2bf_fast(silu_f(st[g][r]));
            } else {
                #pragma unroll
                for (int g = 0; g < 4; g++) {
                    int nc_ = n0 + g * 16 + nn;
                    int id_ = min(nc_, max_id);
                    #pragma unroll
                    for (int r = 0; r < 4; r++) {
                        int mcol = m0 + s * 16 + qd * 4 + r;
                        bool ok = (mcol < id_) || (mcol == nc_);
                        bop[g][r] = (short)f2bf_fast(ok ? silu_f(st[g][r]) : 0.f);
                    }
                }
            }
            #pragma unroll
            for (int t = 0; t < 4; t++) {
                short4v aop = *(const short4v*)&Vt[(t * 16 + nn) * PIT + s * 16 + qd * 4];
                #pragma unroll
                for (int g = 0; g < 4; g++)
                    o_acc[t][g] = __builtin_amdgcn_mfma_f32_16x16x16bf16_1k(aop, bop[g], o_acc[t][g], 0, 0, 0);
            }
        }
        if (mnext <= m_hi) {
            #pragma unroll
            for (int s = 0; s < 4; s++) { kf[s][0] = kn[s][0]; kf[s][1] = kn[s][1]; }
        }
    }

    __syncthreads();
    const float invN = 1.f / (float)NSEQ;
    float* Ow = Os + w * 4352;
    #pragma unroll
    for (int t = 0; t < 4; t++)
        #pragma unroll
        for (int g = 0; g < 4; g++) {
            f32x4 v = o_acc[t][g] * invN;
            *(f32x4*)&Ow[(g * 16 + nn) * 68 + t * 16 + qd * 4] = v;
        }
    __syncthreads();
    int rr = tid >> 2, cs = (tid & 3) * 16;
    if (n0 + rr < len) {
        float* dst = attn + (size_t)(off + n0 + rr) * 256 + h * 64 + cs;
        #pragma unroll
        for (int q4 = 0; q4 < 4; q4++) {
            f32x4 v = (f32x4){0.f, 0.f, 0.f, 0.f};
            #pragma unroll
            for (int w2 = 0; w2 < 4; w2++)
                v += *(const f32x4*)&Os[w2 * 4352 + rr * 68 + cs + q4 * 4];
            *(f32x4*)(dst + q4 * 4) = v;
        }
    }
}

extern "C" void kernel_launch(void* const* d_in, const int* in_sizes, int n_in,
                              void* d_out, int out_size, void* d_ws, size_t ws_size,
                              hipStream_t stream)
{
    const float* x          = (const float*)d_in[0];
    const int*   x_lengths  = (const int*)d_in[1];
    const int*   x_offsets  = (const int*)d_in[2];
    // d_in[3] = max_seq_len (2048, hardcoded as NSEQ)
    const int*   num_targets = (const int*)d_in[4];
    const float* uvqk_w     = (const float*)d_in[5];
    const float* uvqk_b     = (const float*)d_in[6];
    const float* in_w       = (const float*)d_in[7];
    const float* in_b       = (const float*)d_in[8];
    const float* out_w      = (const float*)d_in[9];
    const float* out_b      = (const float*)d_in[10];
    const float* Wo         = (const float*)d_in[11];
    float* out = (float*)d_out;

    int L = in_sizes[0] / 512;   // 6400
    int B = in_sizes[1];         // 4

    char* ws = (char*)d_ws;
    size_t o = 0;
    float* attn = (float*)(ws + o);          o += (size_t)L * 256 * 4;   // fp32 attn
    unsigned short* nxb  = (unsigned short*)(ws + o); o += (size_t)L * 512 * 2;
    unsigned short* A2   = (unsigned short*)(ws + o); o += (size_t)L * 1024 * 2;
    unsigned short* qkvb = (unsigned short*)(ws + o); o += (size_t)L * 768 * 2;
    unsigned short* W1t  = (unsigned short*)(ws + o); o += (size_t)1024 * 512 * 2;
    unsigned short* W2t  = (unsigned short*)(ws + o); o += (size_t)512 * 1024 * 2;

    // 0) weight transpose + cast (per-launch; ~3 MB)
    transpose_to_bf16<<<dim3(1024 / 32, 512 / 32), 256, 0, stream>>>(uvqk_w, W1t, 512, 1024);
    transpose_to_bf16<<<dim3(512 / 32, 1024 / 32), 256, 0, stream>>>(Wo, W2t, 1024, 512);

    // 1) input LN (2 rows/block) -> bf16 nx; raw x -> bf16 A2[:,256:768)
    ln512_kernel<<<L / 2, 256, 0, stream>>>(x, in_w, in_b, nxb, A2);

    // 2) uvqk = silu(nx @ W1 + b): u -> A2[:,0:256), v/q/k -> qkvb  (800 blocks)
    dim3 g1(1024 / 128, L / 64);
    gemm1_mfma<<<g1, 256, 0, stream>>>(nxb, W1t, uvqk_b, A2, qkvb);

    // 3) attention (wave-private m-split, no atomics)
    dim3 g2(NSEQ / 64, 16);
    attn_mfma_kernel<<<g2, 256, 0, stream>>>(qkvb, x_offsets, x_lengths, num_targets, attn);

    // 4) output LN (2 rows/block) -> bf16 A2[:,768:1024)
    ln256_kernel<<<L / 2, 256, 0, stream>>>(attn, out_w, out_b, A2);

    // 5) out = x + A2 @ Wo  (400 blocks)
    dim3 g3(512 / 128, L / 64);
    gemm2_mfma<<<g3, 256, 0, stream>>>(A2, W2t, x, out);
}